// Round 7
// baseline (933.546 us; speedup 1.0000x reference)
//
#include <hip/hip_runtime.h>
#include <stdint.h>

typedef _Float16 f16;
typedef _Float16 f16x8 __attribute__((ext_vector_type(8)));
typedef _Float16 f16x4 __attribute__((ext_vector_type(4)));
typedef float f32x4 __attribute__((ext_vector_type(4)));

#define GAS __attribute__((address_space(1)))
#define LAS __attribute__((address_space(3)))

// async global->LDS, 16 B per lane; LDS dest = wave-uniform base + lane*16
__device__ __forceinline__ void gl_lds16(const void* g, void* l) {
    __builtin_amdgcn_global_load_lds((const GAS uint32_t*)g, (LAS uint32_t*)l, 16, 0, 0);
}

__global__ __launch_bounds__(256) void zerof(float* __restrict__ p, int n) {
    int i = blockIdx.x * 256 + threadIdx.x;
    if (i < n) p[i] = 0.f;
}

__global__ __launch_bounds__(256) void cvt16(const float* __restrict__ in,
                                             f16* __restrict__ o, long n) {
    long i = (long)blockIdx.x * 256 + threadIdx.x;
    if (i < n) o[i] = (f16)in[i];
}

// w [27][Cin][Cout] fp32 -> wt [27][Cout][Cin] fp16 (B-fragment: 16B contiguous Cin)
__global__ __launch_bounds__(256) void wtrans16(const float* __restrict__ w,
                                                f16* __restrict__ wt,
                                                int Cin, int Cout) {
    long i = (long)blockIdx.x * 256 + threadIdx.x;
    long total = 27L * Cin * Cout;
    if (i >= total) return;
    int ci = (int)(i % Cin);
    long t = i / Cin;
    int co = (int)(t % Cout);
    int k  = (int)(t / Cout);
    wt[i] = (f16)w[((long)k * Cin + ci) * Cout + co];
}

// Device-scope grid barrier. Safe because every conv grid is fully co-resident
// (216 blocks @ 1 blk/CU, or 360 @ 2 blk/CU <= 512 slots). Counter is zeroed by
// zerof at the start of every kernel_launch; the counter is monotone within a
// launch, so a stale (already >= target) counter can never deadlock.
__device__ __forceinline__ void gridbar(unsigned* ctr, unsigned target) {
    __threadfence();                    // make this block's stats atomics visible
    __syncthreads();
    if (threadIdx.x == 0) {
        __hip_atomic_fetch_add(ctr, 1u, __ATOMIC_ACQ_REL, __HIP_MEMORY_SCOPE_AGENT);
        while (__hip_atomic_load(ctr, __ATOMIC_ACQUIRE, __HIP_MEMORY_SCOPE_AGENT)
               < target)
            __builtin_amdgcn_s_sleep(8);
    }
    __syncthreads();
}

// Dense implicit 3x3x3 conv, LDS-fed MFMA, round-2 verified tap structure, with
// BN(train)+residual+ReLU FUSED via grid barrier (no cbuf materialization, no
// bn_apply dispatch):
//  taps -> per-block stats atomics -> gridbar -> BN from registers -> store.
//  - A: 10y x 18x halo slab (46080 B). LAYER 0/1: double-buffered per z-stage.
//    LAYER 2: single-buffered (reloaded between stage barriers, round-6 pattern)
//    so LDS = 62.5 KB -> 2 blocks/CU -> all 360 blocks co-resident.
//  - B: per-tap weight panel [COUT][CIN], double-buffered per tap, per-tap
//    __syncthreads drains the DMA (round-2 proven).
//  512 threads = 8 waves = 2 waves/SIMD, r2/c2/k2 split: pairId owns a 64x64
//  (COUT=128) / 32x32 (COUT=32) tile, kh owns a K-half; kh-halves summed via
//  LDS park in the dead B buffers before the grid barrier.
// LAYER 0: CIN=256 (2 halves, 1 in-plane, dz=1-p), COUT=128, grid 216
// LAYER 1: CIN=128, 3 in-planes j=p+dz,   COUT=128, grid 216
// LAYER 2: CIN=128, 3 in-planes j=p+dz-1, COUT=32,  grid 360 (2 blk/CU)
template <int LAYER, bool RESID>
__global__ __launch_bounds__(512, (LAYER == 2) ? 4 : 2) void conv_fused(
    const f16* __restrict__ fin, const f16* __restrict__ wt,
    const f16* __restrict__ zrow, const float* __restrict__ gam,
    const float* __restrict__ bta, const f16* __restrict__ idn,
    f16* __restrict__ outh, float* __restrict__ outf,
    float* __restrict__ stats, unsigned* __restrict__ ctr,
    int nblk, float invM) {
    constexpr int COUT = (LAYER == 2) ? 32 : 128;
    constexpr int INRB = (LAYER == 0) ? 512 : 256;   // input row bytes
    constexpr int WRB  = (LAYER == 0) ? 512 : 256;   // weight row bytes per col
    constexpr int RT   = (COUT == 128) ? 4 : 2;
    constexpr int CT   = (COUT == 128) ? 4 : 2;
    constexpr int NBCH = COUT / 4;                   // B chunks (1 KB each)
    constexpr int BPAN = COUT * 256;                 // B panel bytes
    extern __shared__ char smem[];
    char* ldsA0 = smem;                              // 46080
    char* ldsA1 = (LAYER == 2) ? smem : smem + 46080;  // L2: single slab
    char* ldsB  = smem + ((LAYER == 2) ? 46080 : 92160);

    const int b = blockIdx.x;
    const int p = b / 72;               // out plane
    const int t0 = b % 72;
    const int y0 = (t0 / 6) * 8;
    const int x0 = (t0 % 6) * 16;
    const int tid = threadIdx.x;
    const int lane = tid & 63;
    const int wave = tid >> 6;          // 0..7
    const int kh = wave & 1;            // K-half: kk in {2kh, 2kh+1}
    const int pairId = wave >> 1;       // 0..3 output-tile group
    const int q = lane >> 4;
    const int r16 = lane & 15;
    const int wr = ((COUT == 128) ? (pairId >> 1) : pairId) * (RT * 16);
    const int wc = ((COUT == 128) ? (pairId & 1) : 0) * (CT * 16);

    // stage list (block-uniform): z-planes (and channel halves for LAYER 0)
    int S = 0;
    int js[3], dzs[3], hs[3];
    if (LAYER == 0) {
        js[0] = 0; dzs[0] = 1 - p; hs[0] = 0;
        js[1] = 0; dzs[1] = 1 - p; hs[1] = 1;
        S = 2;
    } else {
        for (int dz = -1; dz <= 1; dz++) {
            int j = (LAYER == 1) ? p + dz : p + dz - 1;
            if (0 <= j && j < 3) { js[S] = j; dzs[S] = dz; hs[S] = 0; S++; }
        }
    }

    auto stageA = [&](int s, char* buf) {
        const int j = js[s], h = hs[s];
        const long pbase = (long)j * 9216;
        for (int ch = wave; ch < 45; ch += 8) {
            int site = ch * 4 + q;
            int sy = site / 18;
            int sx = site - sy * 18;
            int y = y0 - 1 + sy;
            int x = x0 - 1 + sx;
            int cc = r16 ^ (site & 7);
            bool ok = ((unsigned)y < 96u) & ((unsigned)x < 96u);
            const char* src = ok
                ? (const char*)fin + (pbase + y * 96 + x) * INRB + h * 256 + cc * 16
                : (const char*)zrow + cc * 16;
            gl_lds16(src, buf + ch * 1024);
        }
    };
    auto stageB = [&](int k, int h, char* buf) {
        for (int ch = wave; ch < NBCH; ch += 8) {
            int col = ch * 4 + q;
            int cc = r16 ^ (col & 7);
            const char* src = (const char*)wt + (long)(k * COUT + col) * WRB +
                              h * 256 + cc * 16;
            gl_lds16(src, buf + ch * 1024);
        }
    };

    f32x4 acc[RT][CT];
#pragma unroll
    for (int tr = 0; tr < RT; tr++)
#pragma unroll
        for (int c = 0; c < CT; c++) acc[tr][c] = f32x4{0.f, 0.f, 0.f, 0.f};

    const int T = S * 9;
    stageA(0, ldsA0);
    stageB((dzs[0] + 1) * 9, hs[0], ldsB);

    int tap = 0;
    for (int s = 0; s < S; s++) {
        const char* bufA = (LAYER == 2) ? ldsA0 : ((s & 1) ? ldsA1 : ldsA0);
        if (LAYER == 2 && s > 0) {
            __syncthreads();             // prev-stage A reads done
            stageA(s, ldsA0);            // reload the single slab
        }
#pragma unroll
        for (int i = 0; i < 9; i++, tap++) {
            __syncthreads();             // drains DMA for tap (+A stage when due)
            if (LAYER != 2 && i == 0 && s + 1 < S)
                stageA(s + 1, ((s + 1) & 1) ? ldsA1 : ldsA0);
            if (tap + 1 < T) {
                int sn = (i == 8) ? s + 1 : s;
                int in2 = (i == 8) ? 0 : i + 1;
                stageB((dzs[sn] + 1) * 9 + in2, hs[sn],
                       ldsB + ((tap + 1) & 1) * BPAN);
            }
            const char* bufB = ldsB + (tap & 1) * BPAN;
            const int dy = i / 3 - 1, dx = i % 3 - 1;
#pragma unroll
            for (int kk2 = 0; kk2 < 2; kk2++) {
                const int kk = kh * 2 + kk2;
                f16x8 Af[RT], Bf[CT];
#pragma unroll
                for (int tr = 0; tr < RT; tr++) {
                    int site = (wr / 16 + tr + 1 + dy) * 18 + 1 + dx + r16;
                    Af[tr] = *(const f16x8*)(bufA + site * 256 +
                                             (((kk * 4 + q) ^ (site & 7)) << 4));
                }
#pragma unroll
                for (int c = 0; c < CT; c++) {
                    int col = wc + c * 16 + r16;
                    Bf[c] = *(const f16x8*)(bufB + col * 256 +
                                            (((kk * 4 + q) ^ (col & 7)) << 4));
                }
#pragma unroll
                for (int tr = 0; tr < RT; tr++)
#pragma unroll
                    for (int c = 0; c < CT; c++)
                        acc[tr][c] = __builtin_amdgcn_mfma_f32_16x16x32_f16(
                            Af[tr], Bf[c], acc[tr][c], 0, 0, 0);
            }
        }
    }

    // K-half reduction: kh=1 waves park partials in the (now dead) B buffers.
    char* xch = ldsB;                                // 2*BPAN >= 4 * RT*CT KB
    constexpr int XR = RT * CT * 1024;
    __syncthreads();                                 // all tap LDS reads done
    if (kh == 1) {
#pragma unroll
        for (int tr = 0; tr < RT; tr++)
#pragma unroll
            for (int c = 0; c < CT; c++)
                *(f32x4*)(xch + pairId * XR + (tr * CT + c) * 1024 + lane * 16) =
                    acc[tr][c];
    }
    __syncthreads();
    if (kh == 0) {
#pragma unroll
        for (int tr = 0; tr < RT; tr++)
#pragma unroll
            for (int c = 0; c < CT; c++)
                acc[tr][c] += *(const f32x4*)(xch + pairId * XR +
                                              (tr * CT + c) * 1024 + lane * 16);
        // per-channel stats atomics (device scope)
#pragma unroll
        for (int c = 0; c < CT; c++) {
            const int col = wc + c * 16 + r16;
            float sum = 0.f, ssq = 0.f;
#pragma unroll
            for (int tr = 0; tr < RT; tr++)
#pragma unroll
                for (int r = 0; r < 4; r++) {
                    float v = acc[tr][c][r];
                    sum += v;
                    ssq = fmaf(v, v, ssq);
                }
            sum += __shfl_xor(sum, 16);
            sum += __shfl_xor(sum, 32);
            ssq += __shfl_xor(ssq, 16);
            ssq += __shfl_xor(ssq, 32);
            if (q == 0) {
                atomicAdd(&stats[col], sum);
                atomicAdd(&stats[COUT + col], ssq);
            }
        }
    }

    gridbar(ctr, (unsigned)nblk);                    // all blocks' stats done
    if (kh == 1) return;                             // no barriers past this point

    // BN apply from registers (+ residual + ReLU), direct store.
    const long mbase = (long)p * 9216 + (long)y0 * 96 + x0;
#pragma unroll
    for (int c = 0; c < CT; c++) {
        const int col = wc + c * 16 + r16;
        float mu = __hip_atomic_load(&stats[col], __ATOMIC_ACQUIRE,
                                     __HIP_MEMORY_SCOPE_AGENT) * invM;
        float ms = __hip_atomic_load(&stats[COUT + col], __ATOMIC_ACQUIRE,
                                     __HIP_MEMORY_SCOPE_AGENT) * invM;
        float var = fmaxf(ms - mu * mu, 0.f);
        float sc = gam[col] * rsqrtf(var + 1e-5f);
        float bt = bta[col];
#pragma unroll
        for (int tr = 0; tr < RT; tr++) {
            const int ly = wr / 16 + tr;
#pragma unroll
            for (int r = 0; r < 4; r++) {
                const int lx = q * 4 + r;
                const long idx = (mbase + ly * 96 + lx) * COUT + col;
                float v = (acc[tr][c][r] - mu) * sc + bt;
                if (RESID) v += (float)idn[idx];
                v = fmaxf(v, 0.f);
                if (LAYER == 2) outf[idx] = v;
                else outh[idx] = (f16)v;
            }
        }
    }
}

extern "C" void kernel_launch(void* const* d_in, const int* in_sizes, int n_in,
                              void* d_out, int out_size, void* d_ws, size_t ws_size,
                              hipStream_t stream) {
    (void)n_in; (void)out_size; (void)ws_size;
    const float* x    = (const float*)d_in[0];
    const float* w_s1 = (const float*)d_in[1];
    const float* g_s1 = (const float*)d_in[2];
    const float* b_s1 = (const float*)d_in[3];
    const float* w11  = (const float*)d_in[4];
    const float* g11  = (const float*)d_in[5];
    const float* b11  = (const float*)d_in[6];
    const float* w12  = (const float*)d_in[7];
    const float* g12  = (const float*)d_in[8];
    const float* b12  = (const float*)d_in[9];
    const float* w21  = (const float*)d_in[10];
    const float* g21  = (const float*)d_in[11];
    const float* b21  = (const float*)d_in[12];
    const float* w22  = (const float*)d_in[13];
    const float* g22  = (const float*)d_in[14];
    const float* b22  = (const float*)d_in[15];
    const float* w_s2 = (const float*)d_in[16];
    const float* g_s2 = (const float*)d_in[17];
    const float* b_s2 = (const float*)d_in[18];

    const int N0 = in_sizes[0] / 256;   // 9216
    const int M1 = in_sizes[19] / 27;   // 27648
    const int M2 = in_sizes[21] / 27;   // 46080

    char* base = (char*)d_ws;
    size_t off = 0;
    auto alloc = [&](size_t bytes) -> char* {
        off = (off + 255) & ~(size_t)255;
        char* p = base + off;
        off += bytes;
        return p;
    };
    f16* xh  = (f16*)alloc((size_t)N0 * 256 * 2);
    f16* w1  = (f16*)alloc(27UL * 128 * 256 * 2);
    f16* wa1 = (f16*)alloc(27UL * 128 * 128 * 2);
    f16* wa2 = (f16*)alloc(27UL * 128 * 128 * 2);
    f16* wb1 = (f16*)alloc(27UL * 128 * 128 * 2);
    f16* wb2 = (f16*)alloc(27UL * 128 * 128 * 2);
    f16* w2  = (f16*)alloc(27UL * 32 * 128 * 2);
    f16* fA  = (f16*)alloc((size_t)M1 * 128 * 2);
    f16* fB  = (f16*)alloc((size_t)M1 * 128 * 2);
    float*    stats = (float*)alloc(1344UL * 4);     // 6 layers of sum/ssq
    unsigned* ctr   = (unsigned*)alloc(64);          // 6 grid-barrier counters
    f16*      zrow  = (f16*)alloc(512);              // zero site (256 B used)

    const int lds01 = 92160 + 2 * 128 * 256;   // 157696 -> 1 blk/CU
    const int lds2  = 46080 + 2 * 32 * 256;    // 62464  -> 2 blk/CU
    (void)hipFuncSetAttribute((const void*)conv_fused<0, false>,
                              hipFuncAttributeMaxDynamicSharedMemorySize, lds01);
    (void)hipFuncSetAttribute((const void*)conv_fused<1, false>,
                              hipFuncAttributeMaxDynamicSharedMemorySize, lds01);
    (void)hipFuncSetAttribute((const void*)conv_fused<1, true>,
                              hipFuncAttributeMaxDynamicSharedMemorySize, lds01);
    (void)hipFuncSetAttribute((const void*)conv_fused<2, false>,
                              hipFuncAttributeMaxDynamicSharedMemorySize, lds2);

    // stats (5376 B) + ctr (64 B) + pad + zrow (512 B) -> zero 1536 floats
    zerof<<<6, 256, 0, stream>>>(stats, 1536);

    long nx = (long)N0 * 256;
    cvt16<<<(int)((nx + 255) / 256), 256, 0, stream>>>(x, xh, nx);
    wtrans16<<<(27 * 256 * 128 + 255) / 256, 256, 0, stream>>>(w_s1, w1, 256, 128);
    wtrans16<<<(27 * 128 * 128 + 255) / 256, 256, 0, stream>>>(w11, wa1, 128, 128);
    wtrans16<<<(27 * 128 * 128 + 255) / 256, 256, 0, stream>>>(w12, wa2, 128, 128);
    wtrans16<<<(27 * 128 * 128 + 255) / 256, 256, 0, stream>>>(w21, wb1, 128, 128);
    wtrans16<<<(27 * 128 * 128 + 255) / 256, 256, 0, stream>>>(w22, wb2, 128, 128);
    wtrans16<<<(27 * 128 * 32 + 255) / 256, 256, 0, stream>>>(w_s2, w2, 128, 32);

    const float inv1 = 1.f / (float)M1, inv2 = 1.f / (float)M2;
    const int g1 = 3 * 72;              // 216 blocks
    const int g2 = 5 * 72;              // 360 blocks

    // L1: spconv1 (256 -> 128) + BN + ReLU -> fA
    conv_fused<0, false><<<g1, 512, lds01, stream>>>(
        xh, w1, zrow, g_s1, b_s1, nullptr, fA, nullptr, stats, ctr, g1, inv1);
    // Block 1
    conv_fused<1, false><<<g1, 512, lds01, stream>>>(
        fA, wa1, zrow, g11, b11, nullptr, fB, nullptr, stats + 256, ctr + 1, g1, inv1);
    conv_fused<1, true><<<g1, 512, lds01, stream>>>(
        fB, wa2, zrow, g12, b12, fA, fA, nullptr, stats + 512, ctr + 2, g1, inv1);
    // Block 2
    conv_fused<1, false><<<g1, 512, lds01, stream>>>(
        fA, wb1, zrow, g21, b21, nullptr, fB, nullptr, stats + 768, ctr + 3, g1, inv1);
    conv_fused<1, true><<<g1, 512, lds01, stream>>>(
        fB, wb2, zrow, g22, b22, fA, fA, nullptr, stats + 1024, ctr + 4, g1, inv1);
    // L6: spconv2 (128 -> 32) + BN + ReLU -> d_out (fp32)
    conv_fused<2, false><<<g2, 512, lds2, stream>>>(
        fA, w2, zrow, g_s2, b_s2, nullptr, nullptr, (float*)d_out,
        stats + 1280, ctr + 5, g2, inv2);
}

// Round 8
// 450.896 us; speedup vs baseline: 2.0704x; 2.0704x over previous
//
#include <hip/hip_runtime.h>
#include <stdint.h>

typedef _Float16 f16;
typedef _Float16 f16x8 __attribute__((ext_vector_type(8)));
typedef _Float16 f16x4 __attribute__((ext_vector_type(4)));
typedef float f32x4 __attribute__((ext_vector_type(4)));

#define GAS __attribute__((address_space(1)))
#define LAS __attribute__((address_space(3)))

// async global->LDS, 16 B per lane; LDS dest = wave-uniform base + lane*16
__device__ __forceinline__ void gl_lds16(const void* g, void* l) {
    __builtin_amdgcn_global_load_lds((const GAS uint32_t*)g, (LAS uint32_t*)l, 16, 0, 0);
}

// One fused preamble kernel: zero stats+zrow, cvt x->f16 (x4), transpose all 6
// weight tensors fp32 [27][Cin][Cout] -> f16 [27][Cout][Cin].
__device__ __forceinline__ void wt_one(const float* __restrict__ w,
                                       f16* __restrict__ wt, long i,
                                       int Cin, int Cout) {
    int ci = (int)(i % Cin);
    long t = i / Cin;
    int co = (int)(t % Cout);
    int k  = (int)(t / Cout);
    wt[i] = (f16)w[((long)k * Cin + ci) * Cout + co];
}

__global__ __launch_bounds__(256) void prep(
    const float* __restrict__ x, f16* __restrict__ xh, long nx4,
    const float* __restrict__ ws1, f16* __restrict__ w1,
    const float* __restrict__ w11, f16* __restrict__ wa1,
    const float* __restrict__ w12, f16* __restrict__ wa2,
    const float* __restrict__ w21, f16* __restrict__ wb1,
    const float* __restrict__ w22, f16* __restrict__ wb2,
    const float* __restrict__ ws2, f16* __restrict__ w2,
    float* __restrict__ zbuf, long nz) {
    long t = (long)blockIdx.x * 256 + threadIdx.x;
    if (t < nz) { zbuf[t] = 0.f; return; }
    t -= nz;
    if (t < nx4) {                       // cvt16, 4 elems/thread
        float4 v = ((const float4*)x)[t];
        f16x4 o = {(f16)v.x, (f16)v.y, (f16)v.z, (f16)v.w};
        *(f16x4*)(xh + t * 4) = o;
        return;
    }
    t -= nx4;
    if (t < 884736)  { wt_one(ws1, w1, t, 256, 128); return; }
    t -= 884736;
    if (t < 442368)  { wt_one(w11, wa1, t, 128, 128); return; }
    t -= 442368;
    if (t < 442368)  { wt_one(w12, wa2, t, 128, 128); return; }
    t -= 442368;
    if (t < 442368)  { wt_one(w21, wb1, t, 128, 128); return; }
    t -= 442368;
    if (t < 442368)  { wt_one(w22, wb2, t, 128, 128); return; }
    t -= 442368;
    if (t < 110592)  { wt_one(ws2, w2, t, 128, 32); }
}

// Dense implicit 3x3x3 conv, LDS-fed MFMA, round-2 verified tap/sync structure.
//  - A: 10y x 18x halo slab (128ch f16 = 46080 B). LAYER 0/1: double-buffered
//    per z-stage. LAYER 2: single-buffered, reloaded between stage barriers
//    (round-6 verified) -> LDS 62.5 KB -> 2 blocks/CU (all 360 resident).
//  - B: per-tap weight panel [COUT][CIN], double-buffered per TAP; per-tap
//    __syncthreads drains the staged DMA (round-2 proven).
//  WAVE PLAN (the round-8 lever): LAYER 0/1 use 1024 threads = 16 waves =
//  4 waves/SIMD, split r2 x c2 x k4 (kq = wave&3 owns one K-quarter, kkpw=1).
//  Per-wave read:MFMA ratio stays 1:2 (8 reads, 16 MFMA) = round-2 reuse, but
//  the per-SIMD ds_read queue depth doubles -> LDS pipe fed between barriers.
//  LAYER 2 keeps 512 threads (r2c2k2) with 2 blocks/CU giving the same
//  queue-doubling via co-residency. K-parts summed by LDS park tree
//  (round-3-verified) in the dead A/B buffers; kq==0 waves write + BN stats.
// LAYER 0: CIN=256 (2 halves, 1 in-plane, dz=1-p), COUT=128, grid 216
// LAYER 1: CIN=128, 3 in-planes j=p+dz,   COUT=128, grid 216
// LAYER 2: CIN=128, 3 in-planes j=p+dz-1, COUT=32,  grid 360
template <int LAYER>
__global__ __launch_bounds__((LAYER == 2) ? 512 : 1024, 4) void conv_dense(
    const f16* __restrict__ fin, const f16* __restrict__ wt,
    const f16* __restrict__ zrow, float* __restrict__ out,
    float* __restrict__ stats) {
    constexpr int COUT = (LAYER == 2) ? 32 : 128;
    constexpr int INRB = (LAYER == 0) ? 512 : 256;   // input row bytes
    constexpr int WRB  = (LAYER == 0) ? 512 : 256;   // weight row bytes per col
    constexpr int RT   = (COUT == 128) ? 4 : 2;      // 16-row (y) tiles per wave
    constexpr int CT   = (COUT == 128) ? 4 : 2;      // 16-col tiles per wave
    constexpr int NBCH = COUT / 4;                   // B chunks (1 KB each)
    constexpr int BPAN = COUT * 256;                 // B panel bytes
    constexpr int WAVES = (LAYER == 2) ? 8 : 16;
    constexpr int KSPL  = (LAYER == 2) ? 2 : 4;      // K split across waves
    constexpr int KKPW  = 4 / KSPL;                  // kk chunks per wave
    extern __shared__ char smem[];
    char* ldsA0 = smem;                              // 46080
    char* ldsA1 = (LAYER == 2) ? smem : smem + 46080;  // L2: single slab
    char* ldsB  = smem + ((LAYER == 2) ? 46080 : 92160);

    const int b = blockIdx.x;
    const int p = b / 72;               // out plane
    const int t0 = b % 72;
    const int y0 = (t0 / 6) * 8;
    const int x0 = (t0 % 6) * 16;
    const int tid = threadIdx.x;
    const int lane = tid & 63;
    const int wave = tid >> 6;
    const int kq = wave & (KSPL - 1);   // K-part: kk in [kq*KKPW, (kq+1)*KKPW)
    const int pairId = wave / KSPL;     // 0..3 output-tile group
    const int q = lane >> 4;
    const int r16 = lane & 15;
    const int wr = ((COUT == 128) ? (pairId >> 1) : pairId) * (RT * 16);
    const int wc = ((COUT == 128) ? (pairId & 1) : 0) * (CT * 16);

    // stage list (block-uniform): z-planes (and channel halves for LAYER 0)
    int S = 0;
    int js[3], dzs[3], hs[3];
    if (LAYER == 0) {
        js[0] = 0; dzs[0] = 1 - p; hs[0] = 0;
        js[1] = 0; dzs[1] = 1 - p; hs[1] = 1;
        S = 2;
    } else {
        for (int dz = -1; dz <= 1; dz++) {
            int j = (LAYER == 1) ? p + dz : p + dz - 1;
            if (0 <= j && j < 3) { js[S] = j; dzs[S] = dz; hs[S] = 0; S++; }
        }
    }

    auto stageA = [&](int s, char* buf) {
        const int j = js[s], h = hs[s];
        const long pbase = (long)j * 9216;
        for (int ch = wave; ch < 45; ch += WAVES) {
            int site = ch * 4 + q;
            int sy = site / 18;
            int sx = site - sy * 18;
            int y = y0 - 1 + sy;
            int x = x0 - 1 + sx;
            int cc = r16 ^ (site & 7);
            bool ok = ((unsigned)y < 96u) & ((unsigned)x < 96u);
            const char* src = ok
                ? (const char*)fin + (pbase + y * 96 + x) * INRB + h * 256 + cc * 16
                : (const char*)zrow + cc * 16;
            gl_lds16(src, buf + ch * 1024);
        }
    };
    auto stageB = [&](int k, int h, char* buf) {
        for (int ch = wave; ch < NBCH; ch += WAVES) {
            int col = ch * 4 + q;
            int cc = r16 ^ (col & 7);
            const char* src = (const char*)wt + (long)(k * COUT + col) * WRB +
                              h * 256 + cc * 16;
            gl_lds16(src, buf + ch * 1024);
        }
    };

    f32x4 acc[RT][CT];
#pragma unroll
    for (int tr = 0; tr < RT; tr++)
#pragma unroll
        for (int c = 0; c < CT; c++) acc[tr][c] = f32x4{0.f, 0.f, 0.f, 0.f};

    const int T = S * 9;
    stageA(0, ldsA0);
    stageB((dzs[0] + 1) * 9, hs[0], ldsB);

    int tap = 0;
    for (int s = 0; s < S; s++) {
        const char* bufA = (LAYER == 2) ? ldsA0 : ((s & 1) ? ldsA1 : ldsA0);
        if (LAYER == 2 && s > 0) {
            __syncthreads();             // prev-stage A reads done
            stageA(s, ldsA0);            // reload the single slab
        }
#pragma unroll
        for (int i = 0; i < 9; i++, tap++) {
            __syncthreads();             // drains DMA for tap (+A stage when due)
            if (LAYER != 2 && i == 0 && s + 1 < S)
                stageA(s + 1, ((s + 1) & 1) ? ldsA1 : ldsA0);
            if (tap + 1 < T) {
                int sn = (i == 8) ? s + 1 : s;
                int in2 = (i == 8) ? 0 : i + 1;
                stageB((dzs[sn] + 1) * 9 + in2, hs[sn],
                       ldsB + ((tap + 1) & 1) * BPAN);
            }
            const char* bufB = ldsB + (tap & 1) * BPAN;
            const int dy = i / 3 - 1, dx = i % 3 - 1;
#pragma unroll
            for (int kk2 = 0; kk2 < KKPW; kk2++) {
                const int kk = kq * KKPW + kk2;
                f16x8 Af[RT], Bf[CT];
#pragma unroll
                for (int tr = 0; tr < RT; tr++) {
                    int site = (wr / 16 + tr + 1 + dy) * 18 + 1 + dx + r16;
                    Af[tr] = *(const f16x8*)(bufA + site * 256 +
                                             (((kk * 4 + q) ^ (site & 7)) << 4));
                }
#pragma unroll
                for (int c = 0; c < CT; c++) {
                    int col = wc + c * 16 + r16;
                    Bf[c] = *(const f16x8*)(bufB + col * 256 +
                                            (((kk * 4 + q) ^ (col & 7)) << 4));
                }
#pragma unroll
                for (int tr = 0; tr < RT; tr++)
#pragma unroll
                    for (int c = 0; c < CT; c++)
                        acc[tr][c] = __builtin_amdgcn_mfma_f32_16x16x32_f16(
                            Af[tr], Bf[c], acc[tr][c], 0, 0, 0);
            }
        }
    }

    // K-part reduction via LDS park tree (round-3 verified pattern).
    // KSPL=2: kq1 parks region[pairId], kq0 adds. KSPL=4: kq2/kq3 park
    // region[2p]/[2p+1]; kq0/kq1 add; kq1 re-parks [2p+1]; kq0 adds.
    // Regions: 4*HK x RT*CT KB; L01: 8x16KB=128KB (<=156KB smem), L2: 4x4KB.
    char* xch = smem;
    constexpr int HK = KSPL / 2;
    constexpr int XR = RT * CT * 1024;
    __syncthreads();                                 // all tap LDS reads done
    if (kq >= HK) {
#pragma unroll
        for (int tr = 0; tr < RT; tr++)
#pragma unroll
            for (int c = 0; c < CT; c++)
                *(f32x4*)(xch + (pairId * HK + (kq - HK)) * XR +
                          (tr * CT + c) * 1024 + lane * 16) = acc[tr][c];
    }
    __syncthreads();
    if (kq < HK) {
#pragma unroll
        for (int tr = 0; tr < RT; tr++)
#pragma unroll
            for (int c = 0; c < CT; c++)
                acc[tr][c] += *(const f32x4*)(xch + (pairId * HK + kq) * XR +
                                              (tr * CT + c) * 1024 + lane * 16);
    }
    if (HK == 2) {
        if (kq == 1) {
#pragma unroll
            for (int tr = 0; tr < RT; tr++)
#pragma unroll
                for (int c = 0; c < CT; c++)
                    *(f32x4*)(xch + (pairId * 2 + 1) * XR +
                              (tr * CT + c) * 1024 + lane * 16) = acc[tr][c];
        }
        __syncthreads();
        if (kq == 0) {
#pragma unroll
            for (int tr = 0; tr < RT; tr++)
#pragma unroll
                for (int c = 0; c < CT; c++)
                    acc[tr][c] += *(const f32x4*)(xch + (pairId * 2 + 1) * XR +
                                                  (tr * CT + c) * 1024 + lane * 16);
        }
    }
    if (kq != 0) return;                             // no barriers past this point

    // Epilogue: D row = q*4+reg within 16-col (x) tile; write + fused BN stats.
    const long mbase = (long)p * 9216 + (long)y0 * 96 + x0;
#pragma unroll
    for (int c = 0; c < CT; c++) {
        const int col = wc + c * 16 + r16;
        float sum = 0.f, ssq = 0.f;
#pragma unroll
        for (int tr = 0; tr < RT; tr++) {
            const int ly = wr / 16 + tr;
#pragma unroll
            for (int r = 0; r < 4; r++) {
                const int lx = q * 4 + r;
                float v = acc[tr][c][r];
                out[(mbase + ly * 96 + lx) * COUT + col] = v;
                sum += v;
                ssq = fmaf(v, v, ssq);
            }
        }
        sum += __shfl_xor(sum, 16);
        sum += __shfl_xor(sum, 32);
        ssq += __shfl_xor(ssq, 16);
        ssq += __shfl_xor(ssq, 32);
        if (q == 0) {
            atomicAdd(&stats[col], sum);
            atomicAdd(&stats[COUT + col], ssq);
        }
    }
}

// BN(train) + optional residual + ReLU, 4 elems/thread.
__global__ __launch_bounds__(256) void bn_apply4(
    const float4* __restrict__ f, const float* __restrict__ sums,
    const float* __restrict__ g, const float* __restrict__ bta,
    const f16x4* __restrict__ idn, f16* __restrict__ outh,
    float4* __restrict__ outf, long n4, int C, float invM) {
    long i = (long)blockIdx.x * 256 + threadIdx.x;
    if (i >= n4) return;
    int col0 = (int)((i * 4) & (C - 1));
    float4 v = f[i];
    float r[4] = {v.x, v.y, v.z, v.w};
    f16x4 id = {};
    if (idn) id = idn[i];
    f16x4 ho;
#pragma unroll
    for (int j = 0; j < 4; j++) {
        int c = col0 + j;
        float mu = sums[c] * invM;
        float var = sums[C + c] * invM - mu * mu;
        var = fmaxf(var, 0.f);
        float sc = g[c] * rsqrtf(var + 1e-5f);
        float x = (r[j] - mu) * sc + bta[c];
        if (idn) x += (float)id[j];
        x = fmaxf(x, 0.f);
        r[j] = x;
        ho[j] = (f16)x;
    }
    if (outf) outf[i] = make_float4(r[0], r[1], r[2], r[3]);
    else *(f16x4*)(outh + i * 4) = ho;
}

extern "C" void kernel_launch(void* const* d_in, const int* in_sizes, int n_in,
                              void* d_out, int out_size, void* d_ws, size_t ws_size,
                              hipStream_t stream) {
    (void)n_in; (void)out_size; (void)ws_size;
    const float* x    = (const float*)d_in[0];
    const float* w_s1 = (const float*)d_in[1];
    const float* g_s1 = (const float*)d_in[2];
    const float* b_s1 = (const float*)d_in[3];
    const float* w11  = (const float*)d_in[4];
    const float* g11  = (const float*)d_in[5];
    const float* b11  = (const float*)d_in[6];
    const float* w12  = (const float*)d_in[7];
    const float* g12  = (const float*)d_in[8];
    const float* b12  = (const float*)d_in[9];
    const float* w21  = (const float*)d_in[10];
    const float* g21  = (const float*)d_in[11];
    const float* b21  = (const float*)d_in[12];
    const float* w22  = (const float*)d_in[13];
    const float* g22  = (const float*)d_in[14];
    const float* b22  = (const float*)d_in[15];
    const float* w_s2 = (const float*)d_in[16];
    const float* g_s2 = (const float*)d_in[17];
    const float* b_s2 = (const float*)d_in[18];

    const int N0 = in_sizes[0] / 256;   // 9216
    const int M1 = in_sizes[19] / 27;   // 27648
    const int M2 = in_sizes[21] / 27;   // 46080

    char* base = (char*)d_ws;
    size_t off = 0;
    auto alloc = [&](size_t bytes) -> char* {
        off = (off + 255) & ~(size_t)255;
        char* p = base + off;
        off += bytes;
        return p;
    };
    f16* xh  = (f16*)alloc((size_t)N0 * 256 * 2);
    f16* w1  = (f16*)alloc(27UL * 128 * 256 * 2);
    f16* wa1 = (f16*)alloc(27UL * 128 * 128 * 2);
    f16* wa2 = (f16*)alloc(27UL * 128 * 128 * 2);
    f16* wb1 = (f16*)alloc(27UL * 128 * 128 * 2);
    f16* wb2 = (f16*)alloc(27UL * 128 * 128 * 2);
    f16* w2  = (f16*)alloc(27UL * 32 * 128 * 2);
    f16* fA  = (f16*)alloc((size_t)M1 * 128 * 2);
    f16* fB  = (f16*)alloc((size_t)M1 * 128 * 2);
    float* cbuf  = (float*)alloc((size_t)M1 * 128 * 4);  // covers M2*32 too
    float* stats = (float*)alloc(1344UL * 4);            // 5376 B, 256-aligned
    f16*   zrow  = (f16*)alloc(512);                     // zero site (256B used)

    const int lds01 = 92160 + 2 * 128 * 256;   // 157696 -> 1 blk/CU (16 waves)
    const int lds2  = 46080 + 2 * 32 * 256;    // 62464  -> 2 blk/CU
    (void)hipFuncSetAttribute((const void*)conv_dense<0>,
                              hipFuncAttributeMaxDynamicSharedMemorySize, lds01);
    (void)hipFuncSetAttribute((const void*)conv_dense<1>,
                              hipFuncAttributeMaxDynamicSharedMemorySize, lds01);
    (void)hipFuncSetAttribute((const void*)conv_dense<2>,
                              hipFuncAttributeMaxDynamicSharedMemorySize, lds2);

    // Fused preamble: zero stats+zrow (1472 floats), cvt x (x4/thread),
    // transpose all 6 weight tensors. One dispatch.
    const long nz  = 1472;
    const long nx4 = (long)N0 * 256 / 4;                 // 589824
    const long tot = nz + nx4 + 884736 + 4L * 442368 + 110592;
    prep<<<(int)((tot + 255) / 256), 256, 0, stream>>>(
        x, xh, nx4, w_s1, w1, w11, wa1, w12, wa2, w21, wb1, w22, wb2,
        w_s2, w2, stats, nz);

    const float inv1 = 1.f / (float)M1, inv2 = 1.f / (float)M2;
    const int g1 = 3 * 72;              // 216 blocks
    const int g2 = 5 * 72;              // 360 blocks
    const long n4a = (long)M1 * 128 / 4;
    const long n4b = (long)M2 * 32 / 4;
    const int ga = (int)((n4a + 255) / 256);
    const int gb = (int)((n4b + 255) / 256);

    // L1: spconv1 (256 -> 128)
    conv_dense<0><<<g1, 1024, lds01, stream>>>(xh, w1, zrow, cbuf, stats);
    bn_apply4<<<ga, 256, 0, stream>>>((float4*)cbuf, stats, g_s1, b_s1,
                                      nullptr, fA, nullptr, n4a, 128, inv1);
    // Block 1
    conv_dense<1><<<g1, 1024, lds01, stream>>>(fA, wa1, zrow, cbuf, stats + 256);
    bn_apply4<<<ga, 256, 0, stream>>>((float4*)cbuf, stats + 256, g11, b11,
                                      nullptr, fB, nullptr, n4a, 128, inv1);
    conv_dense<1><<<g1, 1024, lds01, stream>>>(fB, wa2, zrow, cbuf, stats + 512);
    bn_apply4<<<ga, 256, 0, stream>>>((float4*)cbuf, stats + 512, g12, b12,
                                      (const f16x4*)fA, fA, nullptr, n4a, 128, inv1);
    // Block 2
    conv_dense<1><<<g1, 1024, lds01, stream>>>(fA, wb1, zrow, cbuf, stats + 768);
    bn_apply4<<<ga, 256, 0, stream>>>((float4*)cbuf, stats + 768, g21, b21,
                                      nullptr, fB, nullptr, n4a, 128, inv1);
    conv_dense<1><<<g1, 1024, lds01, stream>>>(fB, wb2, zrow, cbuf, stats + 1024);
    bn_apply4<<<ga, 256, 0, stream>>>((float4*)cbuf, stats + 1024, g22, b22,
                                      (const f16x4*)fA, fA, nullptr, n4a, 128, inv1);
    // L6: spconv2 (128 -> 32), final fp32 output
    conv_dense<2><<<g2, 512, lds2, stream>>>(fA, w2, zrow, cbuf, stats + 1280);
    bn_apply4<<<gb, 256, 0, stream>>>((float4*)cbuf, stats + 1280, g_s2, b_s2,
                                      nullptr, nullptr, (float4*)d_out, n4b, 32, inv2);
}

// Round 9
// 393.058 us; speedup vs baseline: 2.3751x; 1.1471x over previous
//
#include <hip/hip_runtime.h>
#include <stdint.h>

typedef _Float16 f16;
typedef _Float16 f16x8 __attribute__((ext_vector_type(8)));
typedef _Float16 f16x4 __attribute__((ext_vector_type(4)));
typedef float f32x4 __attribute__((ext_vector_type(4)));

#define GAS __attribute__((address_space(1)))
#define LAS __attribute__((address_space(3)))

// async global->LDS, 16 B per lane; LDS dest = wave-uniform base + lane*16
__device__ __forceinline__ void gl_lds16(const void* g, void* l) {
    __builtin_amdgcn_global_load_lds((const GAS uint32_t*)g, (LAS uint32_t*)l, 16, 0, 0);
}

// One fused preamble kernel (round-8 verified, ~-28 us of glue): zero
// stats+zrow, cvt x->f16 (x4/thread), transpose all 6 weight tensors
// fp32 [27][Cin][Cout] -> f16 [27][Cout][Cin].
__device__ __forceinline__ void wt_one(const float* __restrict__ w,
                                       f16* __restrict__ wt, long i,
                                       int Cin, int Cout) {
    int ci = (int)(i % Cin);
    long t = i / Cin;
    int co = (int)(t % Cout);
    int k  = (int)(t / Cout);
    wt[i] = (f16)w[((long)k * Cin + ci) * Cout + co];
}

__global__ __launch_bounds__(256) void prep(
    const float* __restrict__ x, f16* __restrict__ xh, long nx4,
    const float* __restrict__ ws1, f16* __restrict__ w1,
    const float* __restrict__ w11, f16* __restrict__ wa1,
    const float* __restrict__ w12, f16* __restrict__ wa2,
    const float* __restrict__ w21, f16* __restrict__ wb1,
    const float* __restrict__ w22, f16* __restrict__ wb2,
    const float* __restrict__ ws2, f16* __restrict__ w2,
    float* __restrict__ zbuf, long nz) {
    long t = (long)blockIdx.x * 256 + threadIdx.x;
    if (t < nz) { zbuf[t] = 0.f; return; }
    t -= nz;
    if (t < nx4) {                       // cvt16, 4 elems/thread
        float4 v = ((const float4*)x)[t];
        f16x4 o = {(f16)v.x, (f16)v.y, (f16)v.z, (f16)v.w};
        *(f16x4*)(xh + t * 4) = o;
        return;
    }
    t -= nx4;
    if (t < 884736)  { wt_one(ws1, w1, t, 256, 128); return; }
    t -= 884736;
    if (t < 442368)  { wt_one(w11, wa1, t, 128, 128); return; }
    t -= 442368;
    if (t < 442368)  { wt_one(w12, wa2, t, 128, 128); return; }
    t -= 442368;
    if (t < 442368)  { wt_one(w21, wb1, t, 128, 128); return; }
    t -= 442368;
    if (t < 442368)  { wt_one(w22, wb2, t, 128, 128); return; }
    t -= 442368;
    if (t < 110592)  { wt_one(ws2, w2, t, 128, 32); }
}

// Dense implicit 3x3x3 conv, LDS-fed MFMA — CONSOLIDATED verified structure:
//  round-2 core (best measured: conv<1> ~40 us, VGPR 52, no spill):
//  - A: 10y x 18x halo slab (128ch f16 = 46080 B). LAYER 0/1: double-buffered
//    per z-stage (157.7 KB LDS, 1 blk/CU). LAYER 2: single-buffered, reloaded
//    between stage barriers (round-6/8 verified) -> 62.5 KB -> 2 blk/CU, all
//    360 blocks co-resident (kills the 256+104 two-round dispatch tail).
//  - B: per-tap weight panel [COUT][CIN], double-buffered per TAP; per-tap
//    __syncthreads drains the staged DMA.
//  512 threads = 8 waves = 2 waves/SIMD, split r2/c2/k2: pairId=wave>>1 owns a
//  64x64 (COUT=128) / 32x32 (COUT=32) output tile, kh=wave&1 owns a K-half
//  (kk in {2kh,2kh+1}); K-halves summed via LDS park in the dead B buffers
//  (exactly 4 x RT*CT KB), then kh==0 waves write + fused BN-stats atomics.
// LAYER 0: CIN=256 (2 halves, 1 in-plane, dz=1-p), COUT=128, grid 216
// LAYER 1: CIN=128, 3 in-planes j=p+dz,   COUT=128, grid 216
// LAYER 2: CIN=128, 3 in-planes j=p+dz-1, COUT=32,  grid 360 (2 blk/CU),
//          heavy-planes-first remap (round-3 verified, zero cost).
template <int LAYER>
__global__ __launch_bounds__(512, (LAYER == 2) ? 4 : 2) void conv_dense(
    const f16* __restrict__ fin, const f16* __restrict__ wt,
    const f16* __restrict__ zrow, float* __restrict__ out,
    float* __restrict__ stats) {
    constexpr int COUT = (LAYER == 2) ? 32 : 128;
    constexpr int INRB = (LAYER == 0) ? 512 : 256;   // input row bytes
    constexpr int WRB  = (LAYER == 0) ? 512 : 256;   // weight row bytes per col
    constexpr int RT   = (COUT == 128) ? 4 : 2;      // 16-row tiles per wave
    constexpr int CT   = (COUT == 128) ? 4 : 2;      // 16-col tiles per wave
    constexpr int NBCH = COUT / 4;                   // B chunks (1 KB each)
    constexpr int BPAN = COUT * 256;                 // B panel bytes
    extern __shared__ char smem[];
    char* ldsA0 = smem;                              // 46080
    char* ldsA1 = (LAYER == 2) ? smem : smem + 46080;  // L2: single slab
    char* ldsB  = smem + ((LAYER == 2) ? 46080 : 92160);

    int b = blockIdx.x;
    if (LAYER == 2) {                   // heavy planes dispatch first (perf only)
        const int order[5] = {2, 1, 3, 0, 4};
        b = order[b / 72] * 72 + (b % 72);
    }
    const int p = b / 72;               // out plane
    const int t0 = b % 72;
    const int y0 = (t0 / 6) * 8;
    const int x0 = (t0 % 6) * 16;
    const int tid = threadIdx.x;
    const int lane = tid & 63;
    const int wave = tid >> 6;          // 0..7
    const int kh = wave & 1;            // K-half: kk in {2kh, 2kh+1}
    const int pairId = wave >> 1;       // 0..3 output-tile group
    const int q = lane >> 4;
    const int r16 = lane & 15;
    const int wr = ((COUT == 128) ? (pairId >> 1) : pairId) * (RT * 16);
    const int wc = ((COUT == 128) ? (pairId & 1) : 0) * (CT * 16);

    // stage list (block-uniform): z-planes (and channel halves for LAYER 0)
    int S = 0;
    int js[3], dzs[3], hs[3];
    if (LAYER == 0) {
        js[0] = 0; dzs[0] = 1 - p; hs[0] = 0;
        js[1] = 0; dzs[1] = 1 - p; hs[1] = 1;
        S = 2;
    } else {
        for (int dz = -1; dz <= 1; dz++) {
            int j = (LAYER == 1) ? p + dz : p + dz - 1;
            if (0 <= j && j < 3) { js[S] = j; dzs[S] = dz; hs[S] = 0; S++; }
        }
    }

    auto stageA = [&](int s, char* buf) {
        const int j = js[s], h = hs[s];
        const long pbase = (long)j * 9216;
        for (int ch = wave; ch < 45; ch += 8) {
            int site = ch * 4 + q;
            int sy = site / 18;
            int sx = site - sy * 18;
            int y = y0 - 1 + sy;
            int x = x0 - 1 + sx;
            int cc = r16 ^ (site & 7);
            bool ok = ((unsigned)y < 96u) & ((unsigned)x < 96u);
            const char* src = ok
                ? (const char*)fin + (pbase + y * 96 + x) * INRB + h * 256 + cc * 16
                : (const char*)zrow + cc * 16;
            gl_lds16(src, buf + ch * 1024);
        }
    };
    auto stageB = [&](int k, int h, char* buf) {
        for (int ch = wave; ch < NBCH; ch += 8) {
            int col = ch * 4 + q;
            int cc = r16 ^ (col & 7);
            const char* src = (const char*)wt + (long)(k * COUT + col) * WRB +
                              h * 256 + cc * 16;
            gl_lds16(src, buf + ch * 1024);
        }
    };

    f32x4 acc[RT][CT];
#pragma unroll
    for (int tr = 0; tr < RT; tr++)
#pragma unroll
        for (int c = 0; c < CT; c++) acc[tr][c] = f32x4{0.f, 0.f, 0.f, 0.f};

    const int T = S * 9;
    stageA(0, ldsA0);
    stageB((dzs[0] + 1) * 9, hs[0], ldsB);

    int tap = 0;
    for (int s = 0; s < S; s++) {
        const char* bufA = (LAYER == 2) ? ldsA0 : ((s & 1) ? ldsA1 : ldsA0);
        if (LAYER == 2 && s > 0) {
            __syncthreads();             // prev-stage A reads done
            stageA(s, ldsA0);            // reload the single slab
        }
#pragma unroll
        for (int i = 0; i < 9; i++, tap++) {
            __syncthreads();             // drains DMA for tap (+A stage when due)
            if (LAYER != 2 && i == 0 && s + 1 < S)
                stageA(s + 1, ((s + 1) & 1) ? ldsA1 : ldsA0);
            if (tap + 1 < T) {
                int sn = (i == 8) ? s + 1 : s;
                int in2 = (i == 8) ? 0 : i + 1;
                stageB((dzs[sn] + 1) * 9 + in2, hs[sn],
                       ldsB + ((tap + 1) & 1) * BPAN);
            }
            const char* bufB = ldsB + (tap & 1) * BPAN;
            const int dy = i / 3 - 1, dx = i % 3 - 1;
#pragma unroll
            for (int kk2 = 0; kk2 < 2; kk2++) {
                const int kk = kh * 2 + kk2;
                f16x8 Af[RT], Bf[CT];
#pragma unroll
                for (int tr = 0; tr < RT; tr++) {
                    int site = (wr / 16 + tr + 1 + dy) * 18 + 1 + dx + r16;
                    Af[tr] = *(const f16x8*)(bufA + site * 256 +
                                             (((kk * 4 + q) ^ (site & 7)) << 4));
                }
#pragma unroll
                for (int c = 0; c < CT; c++) {
                    int col = wc + c * 16 + r16;
                    Bf[c] = *(const f16x8*)(bufB + col * 256 +
                                            (((kk * 4 + q) ^ (col & 7)) << 4));
                }
#pragma unroll
                for (int tr = 0; tr < RT; tr++)
#pragma unroll
                    for (int c = 0; c < CT; c++)
                        acc[tr][c] = __builtin_amdgcn_mfma_f32_16x16x32_f16(
                            Af[tr], Bf[c], acc[tr][c], 0, 0, 0);
            }
        }
    }

    // K-half reduction: kh=1 waves park partials in the (now dead) B buffers
    // (2*BPAN = exactly 4 regions x RT*CT KB), kh=0 waves add them.
    char* xch = ldsB;
    constexpr int XR = RT * CT * 1024;
    __syncthreads();                                 // all tap LDS reads done
    if (kh == 1) {
#pragma unroll
        for (int tr = 0; tr < RT; tr++)
#pragma unroll
            for (int c = 0; c < CT; c++)
                *(f32x4*)(xch + pairId * XR + (tr * CT + c) * 1024 + lane * 16) =
                    acc[tr][c];
    }
    __syncthreads();
    if (kh == 1) return;                             // no barriers past this point
#pragma unroll
    for (int tr = 0; tr < RT; tr++)
#pragma unroll
        for (int c = 0; c < CT; c++)
            acc[tr][c] += *(const f32x4*)(xch + pairId * XR + (tr * CT + c) * 1024 +
                                          lane * 16);

    // Epilogue: D row = q*4+reg within 16-col (x) tile; write + fused BN stats.
    const long mbase = (long)p * 9216 + (long)y0 * 96 + x0;
#pragma unroll
    for (int c = 0; c < CT; c++) {
        const int col = wc + c * 16 + r16;
        float sum = 0.f, ssq = 0.f;
#pragma unroll
        for (int tr = 0; tr < RT; tr++) {
            const int ly = wr / 16 + tr;
#pragma unroll
            for (int r = 0; r < 4; r++) {
                const int lx = q * 4 + r;
                float v = acc[tr][c][r];
                out[(mbase + ly * 96 + lx) * COUT + col] = v;
                sum += v;
                ssq = fmaf(v, v, ssq);
            }
        }
        sum += __shfl_xor(sum, 16);
        sum += __shfl_xor(sum, 32);
        ssq += __shfl_xor(ssq, 16);
        ssq += __shfl_xor(ssq, 32);
        if (q == 0) {
            atomicAdd(&stats[col], sum);
            atomicAdd(&stats[COUT + col], ssq);
        }
    }
}

// BN(train) + optional residual + ReLU, 4 elems/thread.
__global__ __launch_bounds__(256) void bn_apply4(
    const float4* __restrict__ f, const float* __restrict__ sums,
    const float* __restrict__ g, const float* __restrict__ bta,
    const f16x4* __restrict__ idn, f16* __restrict__ outh,
    float4* __restrict__ outf, long n4, int C, float invM) {
    long i = (long)blockIdx.x * 256 + threadIdx.x;
    if (i >= n4) return;
    int col0 = (int)((i * 4) & (C - 1));
    float4 v = f[i];
    float r[4] = {v.x, v.y, v.z, v.w};
    f16x4 id = {};
    if (idn) id = idn[i];
    f16x4 ho;
#pragma unroll
    for (int j = 0; j < 4; j++) {
        int c = col0 + j;
        float mu = sums[c] * invM;
        float var = sums[C + c] * invM - mu * mu;
        var = fmaxf(var, 0.f);
        float sc = g[c] * rsqrtf(var + 1e-5f);
        float x = (r[j] - mu) * sc + bta[c];
        if (idn) x += (float)id[j];
        x = fmaxf(x, 0.f);
        r[j] = x;
        ho[j] = (f16)x;
    }
    if (outf) outf[i] = make_float4(r[0], r[1], r[2], r[3]);
    else *(f16x4*)(outh + i * 4) = ho;
}

extern "C" void kernel_launch(void* const* d_in, const int* in_sizes, int n_in,
                              void* d_out, int out_size, void* d_ws, size_t ws_size,
                              hipStream_t stream) {
    (void)n_in; (void)out_size; (void)ws_size;
    const float* x    = (const float*)d_in[0];
    const float* w_s1 = (const float*)d_in[1];
    const float* g_s1 = (const float*)d_in[2];
    const float* b_s1 = (const float*)d_in[3];
    const float* w11  = (const float*)d_in[4];
    const float* g11  = (const float*)d_in[5];
    const float* b11  = (const float*)d_in[6];
    const float* w12  = (const float*)d_in[7];
    const float* g12  = (const float*)d_in[8];
    const float* b12  = (const float*)d_in[9];
    const float* w21  = (const float*)d_in[10];
    const float* g21  = (const float*)d_in[11];
    const float* b21  = (const float*)d_in[12];
    const float* w22  = (const float*)d_in[13];
    const float* g22  = (const float*)d_in[14];
    const float* b22  = (const float*)d_in[15];
    const float* w_s2 = (const float*)d_in[16];
    const float* g_s2 = (const float*)d_in[17];
    const float* b_s2 = (const float*)d_in[18];

    const int N0 = in_sizes[0] / 256;   // 9216
    const int M1 = in_sizes[19] / 27;   // 27648
    const int M2 = in_sizes[21] / 27;   // 46080

    char* base = (char*)d_ws;
    size_t off = 0;
    auto alloc = [&](size_t bytes) -> char* {
        off = (off + 255) & ~(size_t)255;
        char* p = base + off;
        off += bytes;
        return p;
    };
    f16* xh  = (f16*)alloc((size_t)N0 * 256 * 2);
    f16* w1  = (f16*)alloc(27UL * 128 * 256 * 2);
    f16* wa1 = (f16*)alloc(27UL * 128 * 128 * 2);
    f16* wa2 = (f16*)alloc(27UL * 128 * 128 * 2);
    f16* wb1 = (f16*)alloc(27UL * 128 * 128 * 2);
    f16* wb2 = (f16*)alloc(27UL * 128 * 128 * 2);
    f16* w2  = (f16*)alloc(27UL * 32 * 128 * 2);
    f16* fA  = (f16*)alloc((size_t)M1 * 128 * 2);
    f16* fB  = (f16*)alloc((size_t)M1 * 128 * 2);
    float* cbuf  = (float*)alloc((size_t)M1 * 128 * 4);  // covers M2*32 too
    float* stats = (float*)alloc(1344UL * 4);            // 5376 B, 256-aligned
    f16*   zrow  = (f16*)alloc(512);                     // zero site (256B used)

    const int lds01 = 92160 + 2 * 128 * 256;   // 157696 -> 1 blk/CU
    const int lds2  = 46080 + 2 * 32 * 256;    // 62464  -> 2 blk/CU
    (void)hipFuncSetAttribute((const void*)conv_dense<0>,
                              hipFuncAttributeMaxDynamicSharedMemorySize, lds01);
    (void)hipFuncSetAttribute((const void*)conv_dense<1>,
                              hipFuncAttributeMaxDynamicSharedMemorySize, lds01);
    (void)hipFuncSetAttribute((const void*)conv_dense<2>,
                              hipFuncAttributeMaxDynamicSharedMemorySize, lds2);

    // Fused preamble: zero stats+zrow (1472 floats), cvt x (x4/thread),
    // transpose all 6 weight tensors. One dispatch.
    const long nz  = 1472;
    const long nx4 = (long)N0 * 256 / 4;                 // 589824
    const long tot = nz + nx4 + 884736 + 4L * 442368 + 110592;
    prep<<<(int)((tot + 255) / 256), 256, 0, stream>>>(
        x, xh, nx4, w_s1, w1, w11, wa1, w12, wa2, w21, wb1, w22, wb2,
        w_s2, w2, stats, nz);

    const float inv1 = 1.f / (float)M1, inv2 = 1.f / (float)M2;
    const int g1 = 3 * 72;              // 216 blocks
    const int g2 = 5 * 72;              // 360 blocks
    const long n4a = (long)M1 * 128 / 4;
    const long n4b = (long)M2 * 32 / 4;
    const int ga = (int)((n4a + 255) / 256);
    const int gb = (int)((n4b + 255) / 256);

    // L1: spconv1 (256 -> 128)
    conv_dense<0><<<g1, 512, lds01, stream>>>(xh, w1, zrow, cbuf, stats);
    bn_apply4<<<ga, 256, 0, stream>>>((float4*)cbuf, stats, g_s1, b_s1,
                                      nullptr, fA, nullptr, n4a, 128, inv1);
    // Block 1
    conv_dense<1><<<g1, 512, lds01, stream>>>(fA, wa1, zrow, cbuf, stats + 256);
    bn_apply4<<<ga, 256, 0, stream>>>((float4*)cbuf, stats + 256, g11, b11,
                                      nullptr, fB, nullptr, n4a, 128, inv1);
    conv_dense<1><<<g1, 512, lds01, stream>>>(fB, wa2, zrow, cbuf, stats + 512);
    bn_apply4<<<ga, 256, 0, stream>>>((float4*)cbuf, stats + 512, g12, b12,
                                      (const f16x4*)fA, fA, nullptr, n4a, 128, inv1);
    // Block 2
    conv_dense<1><<<g1, 512, lds01, stream>>>(fA, wb1, zrow, cbuf, stats + 768);
    bn_apply4<<<ga, 256, 0, stream>>>((float4*)cbuf, stats + 768, g21, b21,
                                      nullptr, fB, nullptr, n4a, 128, inv1);
    conv_dense<1><<<g1, 512, lds01, stream>>>(fB, wb2, zrow, cbuf, stats + 1024);
    bn_apply4<<<ga, 256, 0, stream>>>((float4*)cbuf, stats + 1024, g22, b22,
                                      (const f16x4*)fA, fA, nullptr, n4a, 128, inv1);
    // L6: spconv2 (128 -> 32), final fp32 output
    conv_dense<2><<<g2, 512, lds2, stream>>>(fA, w2, zrow, cbuf, stats + 1280);
    bn_apply4<<<gb, 256, 0, stream>>>((float4*)cbuf, stats + 1280, g_s2, b_s2,
                                      nullptr, nullptr, (float4*)d_out, n4b, 32, inv2);
}

// Round 10
// 378.071 us; speedup vs baseline: 2.4692x; 1.0396x over previous
//
#include <hip/hip_runtime.h>
#include <stdint.h>

typedef _Float16 f16;
typedef _Float16 f16x8 __attribute__((ext_vector_type(8)));
typedef _Float16 f16x4 __attribute__((ext_vector_type(4)));
typedef float f32x4 __attribute__((ext_vector_type(4)));

#define GAS __attribute__((address_space(1)))
#define LAS __attribute__((address_space(3)))

// async global->LDS, 16 B per lane; LDS dest = wave-uniform base + lane*16
__device__ __forceinline__ void gl_lds16(const void* g, void* l) {
    __builtin_amdgcn_global_load_lds((const GAS uint32_t*)g, (LAS uint32_t*)l, 16, 0, 0);
}

// Fused preamble (one dispatch): blocks [0, nbzc) zero stats+zrow and cvt
// x->f16 (4/thread); blocks [nbzc, nbzc+2700) transpose the 6 weight tensors
// fp32 [27][Cin][Cout] -> f16 [27][Cout][Cin] via 32x32 LDS tiles (round-10:
// coalesced reads 128 B/row, coalesced writes 64 B/row, +1 pad -> no bank
// conflicts; replaces the 512 B-strided reads that over-fetched ~16x).
__global__ __launch_bounds__(256) void prep(
    const float* __restrict__ x, f16* __restrict__ xh, long nx4,
    const float* __restrict__ ws1, f16* __restrict__ w1,
    const float* __restrict__ w11, f16* __restrict__ wa1,
    const float* __restrict__ w12, f16* __restrict__ wa2,
    const float* __restrict__ w21, f16* __restrict__ wb1,
    const float* __restrict__ w22, f16* __restrict__ wb2,
    const float* __restrict__ ws2, f16* __restrict__ w2,
    float* __restrict__ zbuf, long nz, int nbzc) {
    if ((int)blockIdx.x < nbzc) {
        long t = (long)blockIdx.x * 256 + threadIdx.x;
        if (t < nz) { zbuf[t] = 0.f; return; }
        t -= nz;
        if (t < nx4) {                   // cvt16, 4 elems/thread
            float4 v = ((const float4*)x)[t];
            f16x4 o = {(f16)v.x, (f16)v.y, (f16)v.z, (f16)v.w};
            *(f16x4*)(xh + t * 4) = o;
        }
        return;
    }
    int tau = blockIdx.x - nbzc;         // transpose tile id, [0, 2700)
    const float* src; f16* dst; int Cin, Cout;
    if (tau < 864)        { src = ws1; dst = w1;  Cin = 256; Cout = 128; }
    else if (tau < 1296)  { tau -= 864;  src = w11; dst = wa1; Cin = 128; Cout = 128; }
    else if (tau < 1728)  { tau -= 1296; src = w12; dst = wa2; Cin = 128; Cout = 128; }
    else if (tau < 2160)  { tau -= 1728; src = w21; dst = wb1; Cin = 128; Cout = 128; }
    else if (tau < 2592)  { tau -= 2160; src = w22; dst = wb2; Cin = 128; Cout = 128; }
    else                  { tau -= 2592; src = ws2; dst = w2;  Cin = 128; Cout = 32; }
    const int nci = Cin >> 5, nco = Cout >> 5;
    const int k  = tau / (nci * nco);
    const int rm = tau - k * nci * nco;
    const int ci0 = (rm / nco) << 5;
    const int co0 = (rm % nco) << 5;
    __shared__ float tile[32][33];
    const int r = threadIdx.x >> 5, c = threadIdx.x & 31;
#pragma unroll
    for (int i2 = 0; i2 < 4; i2++)
        tile[r + 8 * i2][c] =
            src[((long)(k * Cin + ci0 + r + 8 * i2)) * Cout + co0 + c];
    __syncthreads();
#pragma unroll
    for (int i2 = 0; i2 < 4; i2++)
        dst[((long)(k * Cout + co0 + r + 8 * i2)) * Cin + ci0 + c] =
            (f16)tile[c][r + 8 * i2];
}

// Dense implicit 3x3x3 conv, fully LDS-fed MFMA — EXACT round-2 structure for
// all layers (best measured: conv<1> ~40 us, conv<2> ~43 us, VGPR 52):
//  - A: 10y x 18x halo slab (128ch fp16 = 46080 B), double-buffered per
//    z-stage, DMA'd with global_load_lds (OOB sites -> zrow), XOR swizzle on
//    the global source address.
//  - B: per-tap weight panel [COUT][CIN] (32 KB / 8 KB), double-buffered per
//    TAP: iteration t issues DMA for tap t+1, computes tap t from LDS;
//    per-tap __syncthreads drains the staged DMA.
//  512 threads = 8 waves = 2 waves/SIMD, split r2/c2/k2: pairId=wave>>1 owns a
//  64x64 (COUT=128) / 32x32 (COUT=32) output tile, kh=wave&1 owns a K-half
//  (kk in {2kh,2kh+1}); K-halves summed via LDS park in the dead B buffers,
//  then kh==0 waves write + fused BN-stats atomics.
// LAYER 0: CIN=256 (2 halves, 1 in-plane, dz=1-p), COUT=128, grid 216
// LAYER 1: CIN=128, 3 in-planes, j=p+dz,   COUT=128, grid 216
// LAYER 2: CIN=128, 3 in-planes, j=p+dz-1, COUT=32,  grid 360
template <int LAYER>
__global__ __launch_bounds__(512, 2) void conv_dense(
    const f16* __restrict__ fin, const f16* __restrict__ wt,
    const f16* __restrict__ zrow, float* __restrict__ out,
    float* __restrict__ stats) {
    constexpr int COUT = (LAYER == 2) ? 32 : 128;
    constexpr int INRB = (LAYER == 0) ? 512 : 256;   // input row bytes
    constexpr int WRB  = (LAYER == 0) ? 512 : 256;   // weight row bytes per col
    constexpr int RT   = (COUT == 128) ? 4 : 2;      // 16-row tiles per wave
    constexpr int CT   = (COUT == 128) ? 4 : 2;      // 16-col tiles per wave
    constexpr int NBCH = COUT / 4;                   // B chunks (1 KB each)
    extern __shared__ char smem[];
    char* ldsA0 = smem;                 // 46080
    char* ldsA1 = smem + 46080;         // 46080
    char* ldsB0 = smem + 92160;         // COUT*256
    char* ldsB1 = smem + 92160 + COUT * 256;

    const int b = blockIdx.x;
    const int p = b / 72;               // out plane
    const int t0 = b % 72;
    const int y0 = (t0 / 6) * 8;
    const int x0 = (t0 % 6) * 16;
    const int tid = threadIdx.x;
    const int lane = tid & 63;
    const int wave = tid >> 6;          // 0..7
    const int kh = wave & 1;            // K-half: kk in {2kh, 2kh+1}
    const int pairId = wave >> 1;       // 0..3 output-tile group
    const int q = lane >> 4;
    const int r16 = lane & 15;
    const int wr = ((COUT == 128) ? (pairId >> 1) : pairId) * (RT * 16);
    const int wc = ((COUT == 128) ? (pairId & 1) : 0) * (CT * 16);

    // stage list (block-uniform): z-planes (and channel halves for LAYER 0)
    int S = 0;
    int js[3], dzs[3], hs[3];
    if (LAYER == 0) {
        js[0] = 0; dzs[0] = 1 - p; hs[0] = 0;
        js[1] = 0; dzs[1] = 1 - p; hs[1] = 1;
        S = 2;
    } else {
        for (int dz = -1; dz <= 1; dz++) {
            int j = (LAYER == 1) ? p + dz : p + dz - 1;
            if (0 <= j && j < 3) { js[S] = j; dzs[S] = dz; hs[S] = 0; S++; }
        }
    }

    auto stageA = [&](int s, char* buf) {
        const int j = js[s], h = hs[s];
        const long pbase = (long)j * 9216;
        for (int ch = wave; ch < 45; ch += 8) {
            int site = ch * 4 + q;
            int sy = site / 18;
            int sx = site - sy * 18;
            int y = y0 - 1 + sy;
            int x = x0 - 1 + sx;
            int cc = r16 ^ (site & 7);
            bool ok = ((unsigned)y < 96u) & ((unsigned)x < 96u);
            const char* src = ok
                ? (const char*)fin + (pbase + y * 96 + x) * INRB + h * 256 + cc * 16
                : (const char*)zrow + cc * 16;
            gl_lds16(src, buf + ch * 1024);
        }
    };
    auto stageB = [&](int k, int h, char* buf) {
        for (int ch = wave; ch < NBCH; ch += 8) {
            int col = ch * 4 + q;
            int cc = r16 ^ (col & 7);
            const char* src = (const char*)wt + (long)(k * COUT + col) * WRB +
                              h * 256 + cc * 16;
            gl_lds16(src, buf + ch * 1024);
        }
    };

    f32x4 acc[RT][CT];
#pragma unroll
    for (int tr = 0; tr < RT; tr++)
#pragma unroll
        for (int c = 0; c < CT; c++) acc[tr][c] = f32x4{0.f, 0.f, 0.f, 0.f};

    stageA(0, ldsA0);
    stageB((dzs[0] + 1) * 9, hs[0], ldsB0);

    int tap = 0;
    for (int s = 0; s < S; s++) {
        const char* bufA = (s & 1) ? ldsA1 : ldsA0;
#pragma unroll
        for (int i = 0; i < 9; i++, tap++) {
            __syncthreads();   // drains DMA for tap `tap` (+A stage when due)
            if (i == 0 && s + 1 < S) stageA(s + 1, ((s + 1) & 1) ? ldsA1 : ldsA0);
            if (tap + 1 < S * 9) {
                int sn = (i == 8) ? s + 1 : s;
                int in2 = (i == 8) ? 0 : i + 1;
                stageB((dzs[sn] + 1) * 9 + in2, hs[sn], ((tap + 1) & 1) ? ldsB1 : ldsB0);
            }
            const char* bufB = (tap & 1) ? ldsB1 : ldsB0;
            const int dy = i / 3 - 1, dx = i % 3 - 1;
#pragma unroll
            for (int kk2 = 0; kk2 < 2; kk2++) {
                const int kk = kh * 2 + kk2;
                f16x8 Af[RT], Bf[CT];
#pragma unroll
                for (int tr = 0; tr < RT; tr++) {
                    int site = (wr / 16 + tr + 1 + dy) * 18 + 1 + dx + r16;
                    Af[tr] = *(const f16x8*)(bufA + site * 256 +
                                             (((kk * 4 + q) ^ (site & 7)) << 4));
                }
#pragma unroll
                for (int c = 0; c < CT; c++) {
                    int col = wc + c * 16 + r16;
                    Bf[c] = *(const f16x8*)(bufB + col * 256 +
                                            (((kk * 4 + q) ^ (col & 7)) << 4));
                }
#pragma unroll
                for (int tr = 0; tr < RT; tr++)
#pragma unroll
                    for (int c = 0; c < CT; c++)
                        acc[tr][c] = __builtin_amdgcn_mfma_f32_16x16x32_f16(
                            Af[tr], Bf[c], acc[tr][c], 0, 0, 0);
            }
        }
    }

    // K-half reduction: kh=1 waves park partials in the (now dead) B buffers
    // (2 x COUT*256 B = exactly 4 regions x RT*CT KB), kh=0 waves add them.
    char* xch = smem + 92160;
    constexpr int XR = RT * CT * 1024;
    __syncthreads();                                 // all tap LDS reads done
    if (kh == 1) {
#pragma unroll
        for (int tr = 0; tr < RT; tr++)
#pragma unroll
            for (int c = 0; c < CT; c++)
                *(f32x4*)(xch + pairId * XR + (tr * CT + c) * 1024 + lane * 16) =
                    acc[tr][c];
    }
    __syncthreads();
    if (kh == 1) return;                             // no barriers past this point
#pragma unroll
    for (int tr = 0; tr < RT; tr++)
#pragma unroll
        for (int c = 0; c < CT; c++)
            acc[tr][c] += *(const f32x4*)(xch + pairId * XR + (tr * CT + c) * 1024 +
                                          lane * 16);

    // Epilogue: D row = q*4+reg within 16-col (x) tile; write + fused BN stats.
    const long mbase = (long)p * 9216 + (long)y0 * 96 + x0;
#pragma unroll
    for (int c = 0; c < CT; c++) {
        const int col = wc + c * 16 + r16;
        float sum = 0.f, ssq = 0.f;
#pragma unroll
        for (int tr = 0; tr < RT; tr++) {
            const int ly = wr / 16 + tr;
#pragma unroll
            for (int r = 0; r < 4; r++) {
                const int lx = q * 4 + r;
                float v = acc[tr][c][r];
                out[(mbase + ly * 96 + lx) * COUT + col] = v;
                sum += v;
                ssq = fmaf(v, v, ssq);
            }
        }
        sum += __shfl_xor(sum, 16);
        sum += __shfl_xor(sum, 32);
        ssq += __shfl_xor(ssq, 16);
        ssq += __shfl_xor(ssq, 32);
        if (q == 0) {
            atomicAdd(&stats[col], sum);
            atomicAdd(&stats[COUT + col], ssq);
        }
    }
}

// BN(train) + optional residual + ReLU, 4 elems/thread.
__global__ __launch_bounds__(256) void bn_apply4(
    const float4* __restrict__ f, const float* __restrict__ sums,
    const float* __restrict__ g, const float* __restrict__ bta,
    const f16x4* __restrict__ idn, f16* __restrict__ outh,
    float4* __restrict__ outf, long n4, int C, float invM) {
    long i = (long)blockIdx.x * 256 + threadIdx.x;
    if (i >= n4) return;
    int col0 = (int)((i * 4) & (C - 1));
    float4 v = f[i];
    float r[4] = {v.x, v.y, v.z, v.w};
    f16x4 id = {};
    if (idn) id = idn[i];
    f16x4 ho;
#pragma unroll
    for (int j = 0; j < 4; j++) {
        int c = col0 + j;
        float mu = sums[c] * invM;
        float var = sums[C + c] * invM - mu * mu;
        var = fmaxf(var, 0.f);
        float sc = g[c] * rsqrtf(var + 1e-5f);
        float x = (r[j] - mu) * sc + bta[c];
        if (idn) x += (float)id[j];
        x = fmaxf(x, 0.f);
        r[j] = x;
        ho[j] = (f16)x;
    }
    if (outf) outf[i] = make_float4(r[0], r[1], r[2], r[3]);
    else *(f16x4*)(outh + i * 4) = ho;
}

extern "C" void kernel_launch(void* const* d_in, const int* in_sizes, int n_in,
                              void* d_out, int out_size, void* d_ws, size_t ws_size,
                              hipStream_t stream) {
    (void)n_in; (void)out_size; (void)ws_size;
    const float* x    = (const float*)d_in[0];
    const float* w_s1 = (const float*)d_in[1];
    const float* g_s1 = (const float*)d_in[2];
    const float* b_s1 = (const float*)d_in[3];
    const float* w11  = (const float*)d_in[4];
    const float* g11  = (const float*)d_in[5];
    const float* b11  = (const float*)d_in[6];
    const float* w12  = (const float*)d_in[7];
    const float* g12  = (const float*)d_in[8];
    const float* b12  = (const float*)d_in[9];
    const float* w21  = (const float*)d_in[10];
    const float* g21  = (const float*)d_in[11];
    const float* b21  = (const float*)d_in[12];
    const float* w22  = (const float*)d_in[13];
    const float* g22  = (const float*)d_in[14];
    const float* b22  = (const float*)d_in[15];
    const float* w_s2 = (const float*)d_in[16];
    const float* g_s2 = (const float*)d_in[17];
    const float* b_s2 = (const float*)d_in[18];

    const int N0 = in_sizes[0] / 256;   // 9216
    const int M1 = in_sizes[19] / 27;   // 27648
    const int M2 = in_sizes[21] / 27;   // 46080

    char* base = (char*)d_ws;
    size_t off = 0;
    auto alloc = [&](size_t bytes) -> char* {
        off = (off + 255) & ~(size_t)255;
        char* p = base + off;
        off += bytes;
        return p;
    };
    f16* xh  = (f16*)alloc((size_t)N0 * 256 * 2);
    f16* w1  = (f16*)alloc(27UL * 128 * 256 * 2);
    f16* wa1 = (f16*)alloc(27UL * 128 * 128 * 2);
    f16* wa2 = (f16*)alloc(27UL * 128 * 128 * 2);
    f16* wb1 = (f16*)alloc(27UL * 128 * 128 * 2);
    f16* wb2 = (f16*)alloc(27UL * 128 * 128 * 2);
    f16* w2  = (f16*)alloc(27UL * 32 * 128 * 2);
    f16* fA  = (f16*)alloc((size_t)M1 * 128 * 2);
    f16* fB  = (f16*)alloc((size_t)M1 * 128 * 2);
    float* cbuf  = (float*)alloc((size_t)M1 * 128 * 4);  // covers M2*32 too
    float* stats = (float*)alloc(1344UL * 4);            // 5376 B, 256-aligned
    f16*   zrow  = (f16*)alloc(512);                     // zero site (256B used)

    const int lds01 = 92160 + 2 * 128 * 256;   // 157696 -> 1 blk/CU
    const int lds2  = 92160 + 2 * 32 * 256;    // 108544 -> 1 blk/CU
    (void)hipFuncSetAttribute((const void*)conv_dense<0>,
                              hipFuncAttributeMaxDynamicSharedMemorySize, lds01);
    (void)hipFuncSetAttribute((const void*)conv_dense<1>,
                              hipFuncAttributeMaxDynamicSharedMemorySize, lds01);
    (void)hipFuncSetAttribute((const void*)conv_dense<2>,
                              hipFuncAttributeMaxDynamicSharedMemorySize, lds2);

    // Fused preamble: zero stats(1344)+zrow(128) floats, cvt x (4/thread),
    // then 2700 LDS-tiled 32x32 transpose blocks. One dispatch.
    const long nz  = 1472;
    const long nx4 = (long)N0 * 256 / 4;                 // 589824
    const int nbzc = (int)((nz + nx4 + 255) / 256);      // zero+cvt blocks
    prep<<<nbzc + 2700, 256, 0, stream>>>(
        x, xh, nx4, w_s1, w1, w11, wa1, w12, wa2, w21, wb1, w22, wb2,
        w_s2, w2, stats, nz, nbzc);

    const float inv1 = 1.f / (float)M1, inv2 = 1.f / (float)M2;
    const int g1 = 3 * 72;              // 216 blocks
    const int g2 = 5 * 72;              // 360 blocks
    const long n4a = (long)M1 * 128 / 4;
    const long n4b = (long)M2 * 32 / 4;
    const int ga = (int)((n4a + 255) / 256);
    const int gb = (int)((n4b + 255) / 256);

    // L1: spconv1 (256 -> 128)
    conv_dense<0><<<g1, 512, lds01, stream>>>(xh, w1, zrow, cbuf, stats);
    bn_apply4<<<ga, 256, 0, stream>>>((float4*)cbuf, stats, g_s1, b_s1,
                                      nullptr, fA, nullptr, n4a, 128, inv1);
    // Block 1
    conv_dense<1><<<g1, 512, lds01, stream>>>(fA, wa1, zrow, cbuf, stats + 256);
    bn_apply4<<<ga, 256, 0, stream>>>((float4*)cbuf, stats + 256, g11, b11,
                                      nullptr, fB, nullptr, n4a, 128, inv1);
    conv_dense<1><<<g1, 512, lds01, stream>>>(fB, wa2, zrow, cbuf, stats + 512);
    bn_apply4<<<ga, 256, 0, stream>>>((float4*)cbuf, stats + 512, g12, b12,
                                      (const f16x4*)fA, fA, nullptr, n4a, 128, inv1);
    // Block 2
    conv_dense<1><<<g1, 512, lds01, stream>>>(fA, wb1, zrow, cbuf, stats + 768);
    bn_apply4<<<ga, 256, 0, stream>>>((float4*)cbuf, stats + 768, g21, b21,
                                      nullptr, fB, nullptr, n4a, 128, inv1);
    conv_dense<1><<<g1, 512, lds01, stream>>>(fB, wb2, zrow, cbuf, stats + 1024);
    bn_apply4<<<ga, 256, 0, stream>>>((float4*)cbuf, stats + 1024, g22, b22,
                                      (const f16x4*)fA, fA, nullptr, n4a, 128, inv1);
    // L6: spconv2 (128 -> 32), final fp32 output
    conv_dense<2><<<g2, 512, lds2, stream>>>(fA, w2, zrow, cbuf, stats + 1280);
    bn_apply4<<<gb, 256, 0, stream>>>((float4*)cbuf, stats + 1280, g_s2, b_s2,
                                      nullptr, nullptr, (float4*)d_out, n4b, 32, inv2);
}

// Round 11
// 356.541 us; speedup vs baseline: 2.6183x; 1.0604x over previous
//
#include <hip/hip_runtime.h>
#include <stdint.h>

typedef _Float16 f16;
typedef _Float16 f16x8 __attribute__((ext_vector_type(8)));
typedef _Float16 f16x4 __attribute__((ext_vector_type(4)));
typedef float f32x4 __attribute__((ext_vector_type(4)));

#define GAS __attribute__((address_space(1)))
#define LAS __attribute__((address_space(3)))

// async global->LDS, 16 B per lane; LDS dest = wave-uniform base + lane*16
__device__ __forceinline__ void gl_lds16(const void* g, void* l) {
    __builtin_amdgcn_global_load_lds((const GAS uint32_t*)g, (LAS uint32_t*)l, 16, 0, 0);
}

// Fused preamble (one dispatch): blocks [0, nbzc) zero stats+zrow and cvt
// x->f16 (4/thread); blocks [nbzc, nbzc+2700) transpose the 6 weight tensors
// fp32 [27][Cin][Cout] -> f16 [27][Cout][Cin] via 32x32 LDS tiles (coalesced
// reads/writes, +1 pad -> no bank conflicts; round-10 verified).
__global__ __launch_bounds__(256) void prep(
    const float* __restrict__ x, f16* __restrict__ xh, long nx4,
    const float* __restrict__ ws1, f16* __restrict__ w1,
    const float* __restrict__ w11, f16* __restrict__ wa1,
    const float* __restrict__ w12, f16* __restrict__ wa2,
    const float* __restrict__ w21, f16* __restrict__ wb1,
    const float* __restrict__ w22, f16* __restrict__ wb2,
    const float* __restrict__ ws2, f16* __restrict__ w2,
    float* __restrict__ zbuf, long nz, int nbzc) {
    if ((int)blockIdx.x < nbzc) {
        long t = (long)blockIdx.x * 256 + threadIdx.x;
        if (t < nz) { zbuf[t] = 0.f; return; }
        t -= nz;
        if (t < nx4) {                   // cvt16, 4 elems/thread
            float4 v = ((const float4*)x)[t];
            f16x4 o = {(f16)v.x, (f16)v.y, (f16)v.z, (f16)v.w};
            *(f16x4*)(xh + t * 4) = o;
        }
        return;
    }
    int tau = blockIdx.x - nbzc;         // transpose tile id, [0, 2700)
    const float* src; f16* dst; int Cin, Cout;
    if (tau < 864)        { src = ws1; dst = w1;  Cin = 256; Cout = 128; }
    else if (tau < 1296)  { tau -= 864;  src = w11; dst = wa1; Cin = 128; Cout = 128; }
    else if (tau < 1728)  { tau -= 1296; src = w12; dst = wa2; Cin = 128; Cout = 128; }
    else if (tau < 2160)  { tau -= 1728; src = w21; dst = wb1; Cin = 128; Cout = 128; }
    else if (tau < 2592)  { tau -= 2160; src = w22; dst = wb2; Cin = 128; Cout = 128; }
    else                  { tau -= 2592; src = ws2; dst = w2;  Cin = 128; Cout = 32; }
    const int nci = Cin >> 5, nco = Cout >> 5;
    const int k  = tau / (nci * nco);
    const int rm = tau - k * nci * nco;
    const int ci0 = (rm / nco) << 5;
    const int co0 = (rm % nco) << 5;
    __shared__ float tile[32][33];
    const int r = threadIdx.x >> 5, c = threadIdx.x & 31;
#pragma unroll
    for (int i2 = 0; i2 < 4; i2++)
        tile[r + 8 * i2][c] =
            src[((long)(k * Cin + ci0 + r + 8 * i2)) * Cout + co0 + c];
    __syncthreads();
#pragma unroll
    for (int i2 = 0; i2 < 4; i2++)
        dst[((long)(k * Cout + co0 + r + 8 * i2)) * Cin + ci0 + c] =
            (f16)tile[c][r + 8 * i2];
}

// Dense implicit 3x3x3 conv, round-2 verified tap/sync structure (best
// measured core), with two round-11 additions:
//  - raw conv output stored as f16 (halves epilogue writes + downstream reads)
//  - FOLD: the PRODUCER layer's BN+ReLU (stats final by stream order) is
//    applied during A-staging via reg-staging (load f16x8 -> t=v*sc+bt'
//    [+resid] -> relu -> swizzled ds_write_b128). Each lane's 8 channels are
//    fixed by r16, so (sc,bt') live in 16 VGPRs. OOB sites write literal 0
//    (rulebook gather semantics). Eliminates 3 of 6 bn_apply dispatches.
//  512 threads = 8 waves = 2 waves/SIMD, r2/c2/k2 split; B panels DMA
//  double-buffered per tap; per-tap __syncthreads; K-halves summed via LDS
//  park in the dead B buffers; kh==0 waves write + fused BN-stats atomics.
// LAYER 0: CIN=256 (2 halves, 1 in-plane, dz=1-p), COUT=128, grid 216
// LAYER 1: CIN=128, 3 in-planes, j=p+dz,   COUT=128, grid 216
// LAYER 2: CIN=128, 3 in-planes, j=p+dz-1, COUT=32,  grid 360
template <int LAYER, bool FOLD, bool RESID>
__global__ __launch_bounds__(512, 2) void conv_dense(
    const f16* __restrict__ fin, const f16* __restrict__ wt,
    const f16* __restrict__ zrow, f16* __restrict__ out,
    float* __restrict__ stats,
    const float* __restrict__ pstats, const float* __restrict__ pg,
    const float* __restrict__ pb, const f16* __restrict__ resid,
    float pinv) {
    constexpr int COUT = (LAYER == 2) ? 32 : 128;
    constexpr int INRB = (LAYER == 0) ? 512 : 256;   // input row bytes
    constexpr int WRB  = (LAYER == 0) ? 512 : 256;   // weight row bytes per col
    constexpr int RT   = (COUT == 128) ? 4 : 2;      // 16-row tiles per wave
    constexpr int CT   = (COUT == 128) ? 4 : 2;      // 16-col tiles per wave
    constexpr int NBCH = COUT / 4;                   // B chunks (1 KB each)
    extern __shared__ char smem[];
    char* ldsA0 = smem;                 // 46080
    char* ldsA1 = smem + 46080;         // 46080
    char* ldsB0 = smem + 92160;         // COUT*256
    char* ldsB1 = smem + 92160 + COUT * 256;

    const int b = blockIdx.x;
    const int p = b / 72;               // out plane
    const int t0 = b % 72;
    const int y0 = (t0 / 6) * 8;
    const int x0 = (t0 % 6) * 16;
    const int tid = threadIdx.x;
    const int lane = tid & 63;
    const int wave = tid >> 6;          // 0..7
    const int kh = wave & 1;            // K-half: kk in {2kh, 2kh+1}
    const int pairId = wave >> 1;       // 0..3 output-tile group
    const int q = lane >> 4;
    const int r16 = lane & 15;
    const int wr = ((COUT == 128) ? (pairId >> 1) : pairId) * (RT * 16);
    const int wc = ((COUT == 128) ? (pairId & 1) : 0) * (CT * 16);

    // stage list (block-uniform): z-planes (and channel halves for LAYER 0)
    int S = 0;
    int js[3], dzs[3], hs[3];
    if (LAYER == 0) {
        js[0] = 0; dzs[0] = 1 - p; hs[0] = 0;
        js[1] = 0; dzs[1] = 1 - p; hs[1] = 1;
        S = 2;
    } else {
        for (int dz = -1; dz <= 1; dz++) {
            int j = (LAYER == 1) ? p + dz : p + dz - 1;
            if (0 <= j && j < 3) { js[S] = j; dzs[S] = dz; hs[S] = 0; S++; }
        }
    }

    // Producer BN constants for the fold: channels r16*8+e, fixed per lane.
    float psc[8], pbt[8];
    if (FOLD) {
#pragma unroll
        for (int e = 0; e < 8; e++) {
            int c = r16 * 8 + e;
            float mu = pstats[c] * pinv;
            float var = fmaxf(pstats[128 + c] * pinv - mu * mu, 0.f);
            float s = pg[c] * rsqrtf(var + 1e-5f);
            psc[e] = s;
            pbt[e] = pb[c] - mu * s;
        }
    }

    auto stageA = [&](int s, char* buf) {
        const int j = js[s], h = hs[s];
        const long pbase = (long)j * 9216;
        for (int ch = wave; ch < 45; ch += 8) {
            int site = ch * 4 + q;
            int sy = site / 18;
            int sx = site - sy * 18;
            int y = y0 - 1 + sy;
            int x = x0 - 1 + sx;
            bool ok = ((unsigned)y < 96u) & ((unsigned)x < 96u);
            if (FOLD) {
                // reg-stage: raw f16 -> BN+(resid)+ReLU -> swizzled ds_write
                f16x8 o = {};
                if (ok) {
                    const long ro = (pbase + y * 96 + x) * 128 + r16 * 8;
                    f16x8 v = *(const f16x8*)(fin + ro);
                    f16x8 rv = {};
                    if (RESID) rv = *(const f16x8*)(resid + ro);
#pragma unroll
                    for (int e = 0; e < 8; e++) {
                        float t = (float)v[e] * psc[e] + pbt[e];
                        if (RESID) t += (float)rv[e];
                        o[e] = (f16)fmaxf(t, 0.f);
                    }
                }
                *(f16x8*)(buf + site * 256 + ((r16 ^ (site & 7)) << 4)) = o;
            } else {
                int cc = r16 ^ (site & 7);
                const char* src = ok
                    ? (const char*)fin + (pbase + y * 96 + x) * INRB + h * 256 + cc * 16
                    : (const char*)zrow + cc * 16;
                gl_lds16(src, buf + ch * 1024);
            }
        }
    };
    auto stageB = [&](int k, int h, char* buf) {
        for (int ch = wave; ch < NBCH; ch += 8) {
            int col = ch * 4 + q;
            int cc = r16 ^ (col & 7);
            const char* src = (const char*)wt + (long)(k * COUT + col) * WRB +
                              h * 256 + cc * 16;
            gl_lds16(src, buf + ch * 1024);
        }
    };

    f32x4 acc[RT][CT];
#pragma unroll
    for (int tr = 0; tr < RT; tr++)
#pragma unroll
        for (int c = 0; c < CT; c++) acc[tr][c] = f32x4{0.f, 0.f, 0.f, 0.f};

    stageA(0, ldsA0);
    stageB((dzs[0] + 1) * 9, hs[0], ldsB0);

    int tap = 0;
    for (int s = 0; s < S; s++) {
        const char* bufA = (s & 1) ? ldsA1 : ldsA0;
#pragma unroll
        for (int i = 0; i < 9; i++, tap++) {
            __syncthreads();   // drains DMA + ds_writes for tap (+A stage when due)
            if (i == 0 && s + 1 < S) stageA(s + 1, ((s + 1) & 1) ? ldsA1 : ldsA0);
            if (tap + 1 < S * 9) {
                int sn = (i == 8) ? s + 1 : s;
                int in2 = (i == 8) ? 0 : i + 1;
                stageB((dzs[sn] + 1) * 9 + in2, hs[sn], ((tap + 1) & 1) ? ldsB1 : ldsB0);
            }
            const char* bufB = (tap & 1) ? ldsB1 : ldsB0;
            const int dy = i / 3 - 1, dx = i % 3 - 1;
#pragma unroll
            for (int kk2 = 0; kk2 < 2; kk2++) {
                const int kk = kh * 2 + kk2;
                f16x8 Af[RT], Bf[CT];
#pragma unroll
                for (int tr = 0; tr < RT; tr++) {
                    int site = (wr / 16 + tr + 1 + dy) * 18 + 1 + dx + r16;
                    Af[tr] = *(const f16x8*)(bufA + site * 256 +
                                             (((kk * 4 + q) ^ (site & 7)) << 4));
                }
#pragma unroll
                for (int c = 0; c < CT; c++) {
                    int col = wc + c * 16 + r16;
                    Bf[c] = *(const f16x8*)(bufB + col * 256 +
                                            (((kk * 4 + q) ^ (col & 7)) << 4));
                }
#pragma unroll
                for (int tr = 0; tr < RT; tr++)
#pragma unroll
                    for (int c = 0; c < CT; c++)
                        acc[tr][c] = __builtin_amdgcn_mfma_f32_16x16x32_f16(
                            Af[tr], Bf[c], acc[tr][c], 0, 0, 0);
            }
        }
    }

    // K-half reduction: kh=1 waves park partials in the (now dead) B buffers
    // (2 x COUT*256 B = exactly 4 regions x RT*CT KB), kh=0 waves add them.
    char* xch = smem + 92160;
    constexpr int XR = RT * CT * 1024;
    __syncthreads();                                 // all tap LDS reads done
    if (kh == 1) {
#pragma unroll
        for (int tr = 0; tr < RT; tr++)
#pragma unroll
            for (int c = 0; c < CT; c++)
                *(f32x4*)(xch + pairId * XR + (tr * CT + c) * 1024 + lane * 16) =
                    acc[tr][c];
    }
    __syncthreads();
    if (kh == 1) return;                             // no barriers past this point
#pragma unroll
    for (int tr = 0; tr < RT; tr++)
#pragma unroll
        for (int c = 0; c < CT; c++)
            acc[tr][c] += *(const f32x4*)(xch + pairId * XR + (tr * CT + c) * 1024 +
                                          lane * 16);

    // Epilogue: write raw f16 + fused BN-stats atomics (stats from fp32 acc).
    const long mbase = (long)p * 9216 + (long)y0 * 96 + x0;
#pragma unroll
    for (int c = 0; c < CT; c++) {
        const int col = wc + c * 16 + r16;
        float sum = 0.f, ssq = 0.f;
#pragma unroll
        for (int tr = 0; tr < RT; tr++) {
            const int ly = wr / 16 + tr;
#pragma unroll
            for (int r = 0; r < 4; r++) {
                const int lx = q * 4 + r;
                float v = acc[tr][c][r];
                out[(mbase + ly * 96 + lx) * COUT + col] = (f16)v;
                sum += v;
                ssq = fmaf(v, v, ssq);
            }
        }
        sum += __shfl_xor(sum, 16);
        sum += __shfl_xor(sum, 32);
        ssq += __shfl_xor(ssq, 16);
        ssq += __shfl_xor(ssq, 32);
        if (q == 0) {
            atomicAdd(&stats[col], sum);
            atomicAdd(&stats[COUT + col], ssq);
        }
    }
}

// BN(train) + optional residual + ReLU, 8 f16 elems/thread (16 B loads).
__global__ __launch_bounds__(256) void bn_apply8(
    const f16x8* __restrict__ f, const float* __restrict__ sums,
    const float* __restrict__ g, const float* __restrict__ bta,
    const f16x8* __restrict__ idn, f16* __restrict__ outh,
    float* __restrict__ outf, long n8, int C, float invM) {
    long i = (long)blockIdx.x * 256 + threadIdx.x;
    if (i >= n8) return;
    int col0 = (int)((i * 8) & (C - 1));
    f16x8 v = f[i];
    f16x8 id = {};
    if (idn) id = idn[i];
    f16x8 ho;
    float ro[8];
#pragma unroll
    for (int j = 0; j < 8; j++) {
        int c = col0 + j;
        float mu = sums[c] * invM;
        float var = sums[C + c] * invM - mu * mu;
        var = fmaxf(var, 0.f);
        float sc = g[c] * rsqrtf(var + 1e-5f);
        float x = ((float)v[j] - mu) * sc + bta[c];
        if (idn) x += (float)id[j];
        x = fmaxf(x, 0.f);
        ro[j] = x;
        ho[j] = (f16)x;
    }
    if (outf) {
        *(float4*)(outf + i * 8)     = make_float4(ro[0], ro[1], ro[2], ro[3]);
        *(float4*)(outf + i * 8 + 4) = make_float4(ro[4], ro[5], ro[6], ro[7]);
    } else {
        *(f16x8*)(outh + i * 8) = ho;
    }
}

extern "C" void kernel_launch(void* const* d_in, const int* in_sizes, int n_in,
                              void* d_out, int out_size, void* d_ws, size_t ws_size,
                              hipStream_t stream) {
    (void)n_in; (void)out_size; (void)ws_size;
    const float* x    = (const float*)d_in[0];
    const float* w_s1 = (const float*)d_in[1];
    const float* g_s1 = (const float*)d_in[2];
    const float* b_s1 = (const float*)d_in[3];
    const float* w11  = (const float*)d_in[4];
    const float* g11  = (const float*)d_in[5];
    const float* b11  = (const float*)d_in[6];
    const float* w12  = (const float*)d_in[7];
    const float* g12  = (const float*)d_in[8];
    const float* b12  = (const float*)d_in[9];
    const float* w21  = (const float*)d_in[10];
    const float* g21  = (const float*)d_in[11];
    const float* b21  = (const float*)d_in[12];
    const float* w22  = (const float*)d_in[13];
    const float* g22  = (const float*)d_in[14];
    const float* b22  = (const float*)d_in[15];
    const float* w_s2 = (const float*)d_in[16];
    const float* g_s2 = (const float*)d_in[17];
    const float* b_s2 = (const float*)d_in[18];

    const int N0 = in_sizes[0] / 256;   // 9216
    const int M1 = in_sizes[19] / 27;   // 27648
    const int M2 = in_sizes[21] / 27;   // 46080

    char* base = (char*)d_ws;
    size_t off = 0;
    auto alloc = [&](size_t bytes) -> char* {
        off = (off + 255) & ~(size_t)255;
        char* p = base + off;
        off += bytes;
        return p;
    };
    f16* xh  = (f16*)alloc((size_t)N0 * 256 * 2);
    f16* w1  = (f16*)alloc(27UL * 128 * 256 * 2);
    f16* wa1 = (f16*)alloc(27UL * 128 * 128 * 2);
    f16* wa2 = (f16*)alloc(27UL * 128 * 128 * 2);
    f16* wb1 = (f16*)alloc(27UL * 128 * 128 * 2);
    f16* wb2 = (f16*)alloc(27UL * 128 * 128 * 2);
    f16* w2  = (f16*)alloc(27UL * 32 * 128 * 2);
    f16* fA  = (f16*)alloc((size_t)M1 * 128 * 2);   // f1 (L0 activated)
    f16* fC  = (f16*)alloc((size_t)M1 * 128 * 2);   // f2 (block-1 out)
    f16* rA  = (f16*)alloc((size_t)M1 * 128 * 2);   // raw rotating
    f16* rB  = (f16*)alloc((size_t)M1 * 128 * 2);   // raw rotating
    f16* rS2 = (f16*)alloc((size_t)M2 * 32 * 2);    // raw final conv out
    float* stats = (float*)alloc(1344UL * 4);       // 6 layers of sum/ssq
    f16*   zrow  = (f16*)alloc(512);                // zero site (256B used)

    const int lds01 = 92160 + 2 * 128 * 256;   // 157696 -> 1 blk/CU
    const int lds2  = 92160 + 2 * 32 * 256;    // 108544 -> 1 blk/CU
    (void)hipFuncSetAttribute((const void*)conv_dense<0, false, false>,
                              hipFuncAttributeMaxDynamicSharedMemorySize, lds01);
    (void)hipFuncSetAttribute((const void*)conv_dense<1, false, false>,
                              hipFuncAttributeMaxDynamicSharedMemorySize, lds01);
    (void)hipFuncSetAttribute((const void*)conv_dense<1, true, false>,
                              hipFuncAttributeMaxDynamicSharedMemorySize, lds01);
    (void)hipFuncSetAttribute((const void*)conv_dense<2, true, true>,
                              hipFuncAttributeMaxDynamicSharedMemorySize, lds2);

    // Fused preamble: zero stats(1344)+zrow(128) floats, cvt x (4/thread),
    // then 2700 LDS-tiled 32x32 transpose blocks. One dispatch.
    const long nz  = 1472;
    const long nx4 = (long)N0 * 256 / 4;                 // 589824
    const int nbzc = (int)((nz + nx4 + 255) / 256);      // zero+cvt blocks
    prep<<<nbzc + 2700, 256, 0, stream>>>(
        x, xh, nx4, w_s1, w1, w11, wa1, w12, wa2, w21, wb1, w22, wb2,
        w_s2, w2, stats, nz, nbzc);

    const float inv1 = 1.f / (float)M1, inv2 = 1.f / (float)M2;
    const int g1 = 3 * 72;              // 216 blocks
    const int g2 = 5 * 72;              // 360 blocks
    const long n8a = (long)M1 * 128 / 8;   // 442368
    const long n8b = (long)M2 * 32 / 8;    // 184320
    const int ga = (int)((n8a + 255) / 256);
    const int gb = (int)((n8b + 255) / 256);

    // L1: spconv1 (256 -> 128) -> raw rA + stats1
    conv_dense<0, false, false><<<g1, 512, lds01, stream>>>(
        xh, w1, zrow, rA, stats, nullptr, nullptr, nullptr, nullptr, 0.f);
    // f1 = relu(bn1(rA)) -> fA  (f1 is reused as block-1 residual: materialize)
    bn_apply8<<<ga, 256, 0, stream>>>((const f16x8*)rA, stats, g_s1, b_s1,
                                      nullptr, fA, nullptr, n8a, 128, inv1);
    // conv11: fA -> raw rB + stats11
    conv_dense<1, false, false><<<g1, 512, lds01, stream>>>(
        fA, wa1, zrow, rB, stats + 256, nullptr, nullptr, nullptr, nullptr, 0.f);
    // conv12 with bn11 FOLDED into staging: rB -> raw rA + stats12
    conv_dense<1, true, false><<<g1, 512, lds01, stream>>>(
        rB, wa2, zrow, rA, stats + 512, stats + 256, g11, b11, nullptr, inv1);
    // f2 = relu(bn12(rA) + f1) -> fC  (f2 reused as block-2 residual)
    bn_apply8<<<ga, 256, 0, stream>>>((const f16x8*)rA, stats + 512, g12, b12,
                                      (const f16x8*)fA, fC, nullptr, n8a, 128, inv1);
    // conv21: fC -> raw rB + stats21
    conv_dense<1, false, false><<<g1, 512, lds01, stream>>>(
        fC, wb1, zrow, rB, stats + 768, nullptr, nullptr, nullptr, nullptr, 0.f);
    // conv22 with bn21 FOLDED: rB -> raw rA + stats22
    conv_dense<1, true, false><<<g1, 512, lds01, stream>>>(
        rB, wb2, zrow, rA, stats + 1024, stats + 768, g21, b21, nullptr, inv1);
    // conv_s2 with bn22 + residual(f2) FOLDED: rA -> raw rS2 + statsS2
    conv_dense<2, true, true><<<g2, 512, lds2, stream>>>(
        rA, w2, zrow, rS2, stats + 1280, stats + 1024, g22, b22, fC, inv1);
    // out = relu(bn_s2(rS2)) -> d_out (fp32)
    bn_apply8<<<gb, 256, 0, stream>>>((const f16x8*)rS2, stats + 1280, g_s2, b_s2,
                                      nullptr, nullptr, (float*)d_out, n8b, 32, inv2);
}

// Round 12
// 352.203 us; speedup vs baseline: 2.6506x; 1.0123x over previous
//
#include <hip/hip_runtime.h>
#include <stdint.h>

typedef _Float16 f16;
typedef _Float16 f16x8 __attribute__((ext_vector_type(8)));
typedef _Float16 f16x4 __attribute__((ext_vector_type(4)));
typedef float f32x4 __attribute__((ext_vector_type(4)));

#define GAS __attribute__((address_space(1)))
#define LAS __attribute__((address_space(3)))

// async global->LDS, 16 B per lane; LDS dest = wave-uniform base + lane*16
__device__ __forceinline__ void gl_lds16(const void* g, void* l) {
    __builtin_amdgcn_global_load_lds((const GAS uint32_t*)g, (LAS uint32_t*)l, 16, 0, 0);
}

// Fused preamble (one dispatch): blocks [0, nbzc) zero stats+zrow and cvt
// x->f16 (4/thread); blocks [nbzc, nbzc+2700) transpose the 6 weight tensors
// fp32 [27][Cin][Cout] -> f16 [27][Cout][Cin] via 32x32 LDS tiles (coalesced
// reads/writes, +1 pad -> no bank conflicts; round-10 verified).
__global__ __launch_bounds__(256) void prep(
    const float* __restrict__ x, f16* __restrict__ xh, long nx4,
    const float* __restrict__ ws1, f16* __restrict__ w1,
    const float* __restrict__ w11, f16* __restrict__ wa1,
    const float* __restrict__ w12, f16* __restrict__ wa2,
    const float* __restrict__ w21, f16* __restrict__ wb1,
    const float* __restrict__ w22, f16* __restrict__ wb2,
    const float* __restrict__ ws2, f16* __restrict__ w2,
    float* __restrict__ zbuf, long nz, int nbzc) {
    if ((int)blockIdx.x < nbzc) {
        long t = (long)blockIdx.x * 256 + threadIdx.x;
        if (t < nz) { zbuf[t] = 0.f; return; }
        t -= nz;
        if (t < nx4) {                   // cvt16, 4 elems/thread
            float4 v = ((const float4*)x)[t];
            f16x4 o = {(f16)v.x, (f16)v.y, (f16)v.z, (f16)v.w};
            *(f16x4*)(xh + t * 4) = o;
        }
        return;
    }
    int tau = blockIdx.x - nbzc;         // transpose tile id, [0, 2700)
    const float* src; f16* dst; int Cin, Cout;
    if (tau < 864)        { src = ws1; dst = w1;  Cin = 256; Cout = 128; }
    else if (tau < 1296)  { tau -= 864;  src = w11; dst = wa1; Cin = 128; Cout = 128; }
    else if (tau < 1728)  { tau -= 1296; src = w12; dst = wa2; Cin = 128; Cout = 128; }
    else if (tau < 2160)  { tau -= 1728; src = w21; dst = wb1; Cin = 128; Cout = 128; }
    else if (tau < 2592)  { tau -= 2160; src = w22; dst = wb2; Cin = 128; Cout = 128; }
    else                  { tau -= 2592; src = ws2; dst = w2;  Cin = 128; Cout = 32; }
    const int nci = Cin >> 5, nco = Cout >> 5;
    const int k  = tau / (nci * nco);
    const int rm = tau - k * nci * nco;
    const int ci0 = (rm / nco) << 5;
    const int co0 = (rm % nco) << 5;
    __shared__ float tile[32][33];
    const int r = threadIdx.x >> 5, c = threadIdx.x & 31;
#pragma unroll
    for (int i2 = 0; i2 < 4; i2++)
        tile[r + 8 * i2][c] =
            src[((long)(k * Cin + ci0 + r + 8 * i2)) * Cout + co0 + c];
    __syncthreads();
#pragma unroll
    for (int i2 = 0; i2 < 4; i2++)
        dst[((long)(k * Cout + co0 + r + 8 * i2)) * Cin + ci0 + c] =
            (f16)tile[c][r + 8 * i2];
}

// Dense implicit 3x3x3 conv, round-2 verified tap/sync structure, f16 raw out,
// with producer-BN FOLD (round-11 verified) and round-12 WRITEACT:
//  - FOLD: producer's BN+ReLU (stats final by stream order) applied during
//    A-staging via reg-staging (load f16x8 -> t=v*sc+bt' [+resid] -> relu ->
//    swizzled ds_write_b128). Lane's 8 channels fixed by r16 -> (sc,bt') in
//    16 VGPRs. OOB sites write literal 0 (rulebook gather semantics).
//  - WRITEACT: the OWNER block (stage plane j==p, site in the 8x16 interior:
//    sy in [1,9), sx in [1,17) — an exact 1-1 cover of all 3x96x96 sites
//    across the grid) also writes the activated f16x8 to global, materializing
//    the residual tensor without a bn_apply dispatch. Consumers of that tensor
//    launch later in the stream -> no ordering hazard.
//  Together these remove ALL mid-chain bn_apply dispatches (9 -> 8, only the
//  final BN remains: its stats aren't final until conv_s2 completes).
//  512 threads = 8 waves = 2 waves/SIMD, r2/c2/k2 split; B panels DMA
//  double-buffered per tap; per-tap __syncthreads; K-halves summed via LDS
//  park in the dead B buffers; kh==0 waves write + fused BN-stats atomics.
// LAYER 0: CIN=256 (2 halves, 1 in-plane, dz=1-p), COUT=128, grid 216
// LAYER 1: CIN=128, 3 in-planes, j=p+dz,   COUT=128, grid 216
// LAYER 2: CIN=128, 3 in-planes, j=p+dz-1, COUT=32,  grid 360
template <int LAYER, bool FOLD, bool RESID, bool WRITEACT>
__global__ __launch_bounds__(512, 2) void conv_dense(
    const f16* __restrict__ fin, const f16* __restrict__ wt,
    const f16* __restrict__ zrow, f16* __restrict__ out,
    float* __restrict__ stats,
    const float* __restrict__ pstats, const float* __restrict__ pg,
    const float* __restrict__ pb, const f16* __restrict__ resid,
    f16* __restrict__ actout, float pinv) {
    constexpr int COUT = (LAYER == 2) ? 32 : 128;
    constexpr int INRB = (LAYER == 0) ? 512 : 256;   // input row bytes
    constexpr int WRB  = (LAYER == 0) ? 512 : 256;   // weight row bytes per col
    constexpr int RT   = (COUT == 128) ? 4 : 2;      // 16-row tiles per wave
    constexpr int CT   = (COUT == 128) ? 4 : 2;      // 16-col tiles per wave
    constexpr int NBCH = COUT / 4;                   // B chunks (1 KB each)
    extern __shared__ char smem[];
    char* ldsA0 = smem;                 // 46080
    char* ldsA1 = smem + 46080;         // 46080
    char* ldsB0 = smem + 92160;         // COUT*256
    char* ldsB1 = smem + 92160 + COUT * 256;

    const int b = blockIdx.x;
    const int p = b / 72;               // out plane
    const int t0 = b % 72;
    const int y0 = (t0 / 6) * 8;
    const int x0 = (t0 % 6) * 16;
    const int tid = threadIdx.x;
    const int lane = tid & 63;
    const int wave = tid >> 6;          // 0..7
    const int kh = wave & 1;            // K-half: kk in {2kh, 2kh+1}
    const int pairId = wave >> 1;       // 0..3 output-tile group
    const int q = lane >> 4;
    const int r16 = lane & 15;
    const int wr = ((COUT == 128) ? (pairId >> 1) : pairId) * (RT * 16);
    const int wc = ((COUT == 128) ? (pairId & 1) : 0) * (CT * 16);

    // stage list (block-uniform): z-planes (and channel halves for LAYER 0)
    int S = 0;
    int js[3], dzs[3], hs[3];
    if (LAYER == 0) {
        js[0] = 0; dzs[0] = 1 - p; hs[0] = 0;
        js[1] = 0; dzs[1] = 1 - p; hs[1] = 1;
        S = 2;
    } else {
        for (int dz = -1; dz <= 1; dz++) {
            int j = (LAYER == 1) ? p + dz : p + dz - 1;
            if (0 <= j && j < 3) { js[S] = j; dzs[S] = dz; hs[S] = 0; S++; }
        }
    }

    // Producer BN constants for the fold: channels r16*8+e, fixed per lane.
    float psc[8], pbt[8];
    if (FOLD) {
#pragma unroll
        for (int e = 0; e < 8; e++) {
            int c = r16 * 8 + e;
            float mu = pstats[c] * pinv;
            float var = fmaxf(pstats[128 + c] * pinv - mu * mu, 0.f);
            float s = pg[c] * rsqrtf(var + 1e-5f);
            psc[e] = s;
            pbt[e] = pb[c] - mu * s;
        }
    }

    auto stageA = [&](int s, char* buf) {
        const int j = js[s], h = hs[s];
        const long pbase = (long)j * 9216;
        for (int ch = wave; ch < 45; ch += 8) {
            int site = ch * 4 + q;
            int sy = site / 18;
            int sx = site - sy * 18;
            int y = y0 - 1 + sy;
            int x = x0 - 1 + sx;
            bool ok = ((unsigned)y < 96u) & ((unsigned)x < 96u);
            if (FOLD) {
                // reg-stage: raw f16 -> BN+(resid)+ReLU -> swizzled ds_write
                f16x8 o = {};
                if (ok) {
                    const long ro = (pbase + y * 96 + x) * 128 + r16 * 8;
                    f16x8 v = *(const f16x8*)(fin + ro);
                    f16x8 rv = {};
                    if (RESID) rv = *(const f16x8*)(resid + ro);
#pragma unroll
                    for (int e = 0; e < 8; e++) {
                        float t = (float)v[e] * psc[e] + pbt[e];
                        if (RESID) t += (float)rv[e];
                        o[e] = (f16)fmaxf(t, 0.f);
                    }
                    // Owner write: materialize the activated tensor (exactly
                    // one block owns each (plane, y, x) site).
                    if (WRITEACT && j == p &&
                        (unsigned)(sy - 1) < 8u && (unsigned)(sx - 1) < 16u)
                        *(f16x8*)(actout + ro) = o;
                }
                *(f16x8*)(buf + site * 256 + ((r16 ^ (site & 7)) << 4)) = o;
            } else {
                int cc = r16 ^ (site & 7);
                const char* src = ok
                    ? (const char*)fin + (pbase + y * 96 + x) * INRB + h * 256 + cc * 16
                    : (const char*)zrow + cc * 16;
                gl_lds16(src, buf + ch * 1024);
            }
        }
    };
    auto stageB = [&](int k, int h, char* buf) {
        for (int ch = wave; ch < NBCH; ch += 8) {
            int col = ch * 4 + q;
            int cc = r16 ^ (col & 7);
            const char* src = (const char*)wt + (long)(k * COUT + col) * WRB +
                              h * 256 + cc * 16;
            gl_lds16(src, buf + ch * 1024);
        }
    };

    f32x4 acc[RT][CT];
#pragma unroll
    for (int tr = 0; tr < RT; tr++)
#pragma unroll
        for (int c = 0; c < CT; c++) acc[tr][c] = f32x4{0.f, 0.f, 0.f, 0.f};

    stageA(0, ldsA0);
    stageB((dzs[0] + 1) * 9, hs[0], ldsB0);

    int tap = 0;
    for (int s = 0; s < S; s++) {
        const char* bufA = (s & 1) ? ldsA1 : ldsA0;
#pragma unroll
        for (int i = 0; i < 9; i++, tap++) {
            __syncthreads();   // drains DMA + ds_writes for tap (+A stage when due)
            if (i == 0 && s + 1 < S) stageA(s + 1, ((s + 1) & 1) ? ldsA1 : ldsA0);
            if (tap + 1 < S * 9) {
                int sn = (i == 8) ? s + 1 : s;
                int in2 = (i == 8) ? 0 : i + 1;
                stageB((dzs[sn] + 1) * 9 + in2, hs[sn], ((tap + 1) & 1) ? ldsB1 : ldsB0);
            }
            const char* bufB = (tap & 1) ? ldsB1 : ldsB0;
            const int dy = i / 3 - 1, dx = i % 3 - 1;
#pragma unroll
            for (int kk2 = 0; kk2 < 2; kk2++) {
                const int kk = kh * 2 + kk2;
                f16x8 Af[RT], Bf[CT];
#pragma unroll
                for (int tr = 0; tr < RT; tr++) {
                    int site = (wr / 16 + tr + 1 + dy) * 18 + 1 + dx + r16;
                    Af[tr] = *(const f16x8*)(bufA + site * 256 +
                                             (((kk * 4 + q) ^ (site & 7)) << 4));
                }
#pragma unroll
                for (int c = 0; c < CT; c++) {
                    int col = wc + c * 16 + r16;
                    Bf[c] = *(const f16x8*)(bufB + col * 256 +
                                            (((kk * 4 + q) ^ (col & 7)) << 4));
                }
#pragma unroll
                for (int tr = 0; tr < RT; tr++)
#pragma unroll
                    for (int c = 0; c < CT; c++)
                        acc[tr][c] = __builtin_amdgcn_mfma_f32_16x16x32_f16(
                            Af[tr], Bf[c], acc[tr][c], 0, 0, 0);
            }
        }
    }

    // K-half reduction: kh=1 waves park partials in the (now dead) B buffers
    // (2 x COUT*256 B = exactly 4 regions x RT*CT KB), kh=0 waves add them.
    char* xch = smem + 92160;
    constexpr int XR = RT * CT * 1024;
    __syncthreads();                                 // all tap LDS reads done
    if (kh == 1) {
#pragma unroll
        for (int tr = 0; tr < RT; tr++)
#pragma unroll
            for (int c = 0; c < CT; c++)
                *(f32x4*)(xch + pairId * XR + (tr * CT + c) * 1024 + lane * 16) =
                    acc[tr][c];
    }
    __syncthreads();
    if (kh == 1) return;                             // no barriers past this point
#pragma unroll
    for (int tr = 0; tr < RT; tr++)
#pragma unroll
        for (int c = 0; c < CT; c++)
            acc[tr][c] += *(const f32x4*)(xch + pairId * XR + (tr * CT + c) * 1024 +
                                          lane * 16);

    // Epilogue: write raw f16 + fused BN-stats atomics (stats from fp32 acc).
    const long mbase = (long)p * 9216 + (long)y0 * 96 + x0;
#pragma unroll
    for (int c = 0; c < CT; c++) {
        const int col = wc + c * 16 + r16;
        float sum = 0.f, ssq = 0.f;
#pragma unroll
        for (int tr = 0; tr < RT; tr++) {
            const int ly = wr / 16 + tr;
#pragma unroll
            for (int r = 0; r < 4; r++) {
                const int lx = q * 4 + r;
                float v = acc[tr][c][r];
                out[(mbase + ly * 96 + lx) * COUT + col] = (f16)v;
                sum += v;
                ssq = fmaf(v, v, ssq);
            }
        }
        sum += __shfl_xor(sum, 16);
        sum += __shfl_xor(sum, 32);
        ssq += __shfl_xor(ssq, 16);
        ssq += __shfl_xor(ssq, 32);
        if (q == 0) {
            atomicAdd(&stats[col], sum);
            atomicAdd(&stats[COUT + col], ssq);
        }
    }
}

// BN(train) + ReLU, 8 f16 elems/thread (final layer only).
__global__ __launch_bounds__(256) void bn_apply8(
    const f16x8* __restrict__ f, const float* __restrict__ sums,
    const float* __restrict__ g, const float* __restrict__ bta,
    float* __restrict__ outf, long n8, int C, float invM) {
    long i = (long)blockIdx.x * 256 + threadIdx.x;
    if (i >= n8) return;
    int col0 = (int)((i * 8) & (C - 1));
    f16x8 v = f[i];
    float ro[8];
#pragma unroll
    for (int j = 0; j < 8; j++) {
        int c = col0 + j;
        float mu = sums[c] * invM;
        float var = sums[C + c] * invM - mu * mu;
        var = fmaxf(var, 0.f);
        float sc = g[c] * rsqrtf(var + 1e-5f);
        ro[j] = fmaxf(((float)v[j] - mu) * sc + bta[c], 0.f);
    }
    *(float4*)(outf + i * 8)     = make_float4(ro[0], ro[1], ro[2], ro[3]);
    *(float4*)(outf + i * 8 + 4) = make_float4(ro[4], ro[5], ro[6], ro[7]);
}

extern "C" void kernel_launch(void* const* d_in, const int* in_sizes, int n_in,
                              void* d_out, int out_size, void* d_ws, size_t ws_size,
                              hipStream_t stream) {
    (void)n_in; (void)out_size; (void)ws_size;
    const float* x    = (const float*)d_in[0];
    const float* w_s1 = (const float*)d_in[1];
    const float* g_s1 = (const float*)d_in[2];
    const float* b_s1 = (const float*)d_in[3];
    const float* w11  = (const float*)d_in[4];
    const float* g11  = (const float*)d_in[5];
    const float* b11  = (const float*)d_in[6];
    const float* w12  = (const float*)d_in[7];
    const float* g12  = (const float*)d_in[8];
    const float* b12  = (const float*)d_in[9];
    const float* w21  = (const float*)d_in[10];
    const float* g21  = (const float*)d_in[11];
    const float* b21  = (const float*)d_in[12];
    const float* w22  = (const float*)d_in[13];
    const float* g22  = (const float*)d_in[14];
    const float* b22  = (const float*)d_in[15];
    const float* w_s2 = (const float*)d_in[16];
    const float* g_s2 = (const float*)d_in[17];
    const float* b_s2 = (const float*)d_in[18];

    const int N0 = in_sizes[0] / 256;   // 9216
    const int M1 = in_sizes[19] / 27;   // 27648
    const int M2 = in_sizes[21] / 27;   // 46080

    char* base = (char*)d_ws;
    size_t off = 0;
    auto alloc = [&](size_t bytes) -> char* {
        off = (off + 255) & ~(size_t)255;
        char* p = base + off;
        off += bytes;
        return p;
    };
    f16* xh  = (f16*)alloc((size_t)N0 * 256 * 2);
    f16* w1  = (f16*)alloc(27UL * 128 * 256 * 2);
    f16* wa1 = (f16*)alloc(27UL * 128 * 128 * 2);
    f16* wa2 = (f16*)alloc(27UL * 128 * 128 * 2);
    f16* wb1 = (f16*)alloc(27UL * 128 * 128 * 2);
    f16* wb2 = (f16*)alloc(27UL * 128 * 128 * 2);
    f16* w2  = (f16*)alloc(27UL * 32 * 128 * 2);
    f16* fA  = (f16*)alloc((size_t)M1 * 128 * 2);   // f1 (owner-written by conv11)
    f16* fC  = (f16*)alloc((size_t)M1 * 128 * 2);   // f2 (owner-written by conv21)
    f16* rA  = (f16*)alloc((size_t)M1 * 128 * 2);   // raw rotating
    f16* rB  = (f16*)alloc((size_t)M1 * 128 * 2);   // raw rotating
    f16* rS2 = (f16*)alloc((size_t)M2 * 32 * 2);    // raw final conv out
    float* stats = (float*)alloc(1344UL * 4);       // 6 layers of sum/ssq
    f16*   zrow  = (f16*)alloc(512);                // zero site (256B used)

    const int lds01 = 92160 + 2 * 128 * 256;   // 157696 -> 1 blk/CU
    const int lds2  = 92160 + 2 * 32 * 256;    // 108544 -> 1 blk/CU
    (void)hipFuncSetAttribute((const void*)conv_dense<0, false, false, false>,
                              hipFuncAttributeMaxDynamicSharedMemorySize, lds01);
    (void)hipFuncSetAttribute((const void*)conv_dense<1, true, false, true>,
                              hipFuncAttributeMaxDynamicSharedMemorySize, lds01);
    (void)hipFuncSetAttribute((const void*)conv_dense<1, true, false, false>,
                              hipFuncAttributeMaxDynamicSharedMemorySize, lds01);
    (void)hipFuncSetAttribute((const void*)conv_dense<1, true, true, true>,
                              hipFuncAttributeMaxDynamicSharedMemorySize, lds01);
    (void)hipFuncSetAttribute((const void*)conv_dense<2, true, true, false>,
                              hipFuncAttributeMaxDynamicSharedMemorySize, lds2);

    // Fused preamble: zero stats(1344)+zrow(128) floats, cvt x (4/thread),
    // then 2700 LDS-tiled 32x32 transpose blocks. One dispatch.
    const long nz  = 1472;
    const long nx4 = (long)N0 * 256 / 4;                 // 589824
    const int nbzc = (int)((nz + nx4 + 255) / 256);      // zero+cvt blocks
    prep<<<nbzc + 2700, 256, 0, stream>>>(
        x, xh, nx4, w_s1, w1, w11, wa1, w12, wa2, w21, wb1, w22, wb2,
        w_s2, w2, stats, nz, nbzc);

    const float inv1 = 1.f / (float)M1, inv2 = 1.f / (float)M2;
    const int g1 = 3 * 72;              // 216 blocks
    const int g2 = 5 * 72;              // 360 blocks
    const long n8b = (long)M2 * 32 / 8; // 184320
    const int gb = (int)((n8b + 255) / 256);

    // conv0: xh -> raw rA + stats0
    conv_dense<0, false, false, false><<<g1, 512, lds01, stream>>>(
        xh, w1, zrow, rA, stats, nullptr, nullptr, nullptr, nullptr, nullptr, 0.f);
    // conv11, FOLD(bn0) + WRITEACT(fA): rA -> raw rB + stats11
    conv_dense<1, true, false, true><<<g1, 512, lds01, stream>>>(
        rA, wa1, zrow, rB, stats + 256, stats, g_s1, b_s1, nullptr, fA, inv1);
    // conv12, FOLD(bn11): rB -> raw rA + stats12
    conv_dense<1, true, false, false><<<g1, 512, lds01, stream>>>(
        rB, wa2, zrow, rA, stats + 512, stats + 256, g11, b11, nullptr, nullptr, inv1);
    // conv21, FOLD(bn12) + RESID(fA) + WRITEACT(fC): rA -> raw rB + stats21
    conv_dense<1, true, true, true><<<g1, 512, lds01, stream>>>(
        rA, wb1, zrow, rB, stats + 768, stats + 512, g12, b12, fA, fC, inv1);
    // conv22, FOLD(bn21): rB -> raw rA + stats22
    conv_dense<1, true, false, false><<<g1, 512, lds01, stream>>>(
        rB, wb2, zrow, rA, stats + 1024, stats + 768, g21, b21, nullptr, nullptr, inv1);
    // conv_s2, FOLD(bn22) + RESID(fC): rA -> raw rS2 + statsS2
    conv_dense<2, true, true, false><<<g2, 512, lds2, stream>>>(
        rA, w2, zrow, rS2, stats + 1280, stats + 1024, g22, b22, fC, nullptr, inv1);
    // final BN (stats not final until conv_s2 completes): rS2 -> d_out (fp32)
    bn_apply8<<<gb, 256, 0, stream>>>((const f16x8*)rS2, stats + 1280, g_s2, b_s2,
                                      (float*)d_out, n8b, 32, inv2);
}